// Round 2
// baseline (779.529 us; speedup 1.0000x reference)
//
#include <hip/hip_runtime.h>

typedef unsigned short u16;
typedef unsigned int u32;

#define EPSBN 0.001f

__device__ __forceinline__ float bf2f(u16 u) {
    return __uint_as_float(((u32)u) << 16);
}
__device__ __forceinline__ u16 f2bf(float f) {
    u32 u = __float_as_uint(f);
    u32 r = u + 0x7FFFu + ((u >> 16) & 1u);
    return (u16)(r >> 16);
}
__device__ __forceinline__ float relu(float x) { return x > 0.f ? x : 0.f; }

// ---------------- ws layout (float offsets) ----------------
#define A_INPUTS 64       // 196608
#define A_TC1W  196672    // 192
#define A_TC1B  196864    // 64
#define A_TBN1  196928    // 256
#define A_TD1W  197184    // 4096
#define A_TD1B  201280    // 64
#define A_TBN2  201344    // 256
#define A_TD2W  201600    // 576
#define A_TD2B  202176    // 9
#define A_C1W   202240    // 12288
#define A_C1B   214528    // 128
#define A_BN1   214656    // 512
#define A_C2W   215168    // 32768
#define A_C2B   247936    // 256
#define A_BN2   248192    // 1024
#define A_BN3   249216    // 1024
#define A_D1W   250240    // 768
#define A_D1B   251008    // 3
#define A_C3W   251072    // 1536
#define A_C3B   252608    // 512
#define A_BN4   253120    // 2048
#define A_BLK1W 255168    // 131072
#define A_BLK1B 386240    // 256
#define A_BLK1BN 386496   // 1024
#define A_BLK2W 387520    // 32768
#define A_BLK2B 420288    // 128
#define A_BLK2BN 420416   // 512
#define A_BNGF  420928    // 512
#define S_XMAX  421440    // 2048
#define S_TRF   423488    // 288
#define S_PCT   423808    // 196704 (32*2049*3)
#define S_MAXF  620544    // 8192 u32
#define S_NETMAX 628736   // 4096 u32  (end 632832 floats = 2.53 MB)

struct ConvArgs {
    const void* src[28];
    int n[28];
    int off[28];
};

// ---------------- detect: bf16 vs f32 inputs ----------------
__global__ __launch_bounds__(64) void k_detect(const u16* __restrict__ tbn1, u32* __restrict__ flag) {
    if (threadIdx.x == 0) {
        int ok = 1;
        for (int i = 0; i < 16; i += 2) {
            u16 v = tbn1[i];  // gamma ~ 1.0 +- 0.1 if bf16
            if (v < 0x3E00u || v > 0x4080u) ok = 0;
        }
        flag[0] = ok ? 1u : 0u;  // 1 = bf16, 0 = f32
    }
}

// ---------------- convert all float tensors to f32 arena ----------------
__global__ __launch_bounds__(256) void k_convert(ConvArgs a, float* __restrict__ ws, const u32* __restrict__ flag) {
    int t = blockIdx.y;
    int n = a.n[t];
    int cpb = (n + 31) >> 5;
    int s = blockIdx.x * cpb;
    int e = s + cpb; if (e > n) e = n;
    int isbf = (int)flag[0];
    float* dst = ws + a.off[t];
    if (isbf) {
        const u16* src = (const u16*)a.src[t];
        for (int i = s + (int)threadIdx.x; i < e; i += 256) dst[i] = bf2f(src[i]);
    } else {
        const float* src = (const float*)a.src[t];
        for (int i = s + (int)threadIdx.x; i < e; i += 256) dst[i] = src[i];
    }
}

// ---------------- K1: t-net stage 1 ----------------
__global__ __launch_bounds__(256) void k_tnet1(const float* __restrict__ inp,
                                               const float* __restrict__ w,
                                               const float* __restrict__ bias,
                                               const float* __restrict__ bn,
                                               float* __restrict__ xmax) {
    int b = blockIdx.x;
    int tid = threadIdx.x;
    __shared__ float W0[64], W1[64], W2[64], S[64], T[64], Bv[64];
    __shared__ u32 smax[64];
    if (tid < 64) {
        W0[tid] = w[tid];
        W1[tid] = w[64 + tid];
        W2[tid] = w[128 + tid];
        float g = bn[tid], be = bn[64 + tid], m = bn[128 + tid], v = bn[192 + tid];
        float s = g * rsqrtf(v + EPSBN);
        S[tid] = s; T[tid] = be - m * s;
        Bv[tid] = bias[tid];
        smax[tid] = 0u;
    }
    __syncthreads();
    float mx[64];
#pragma unroll
    for (int c = 0; c < 64; c++) mx[c] = 0.f;  // relu >= 0
    const float* ip = inp + (size_t)b * 2048 * 3;
    for (int n = tid; n < 2048; n += 256) {
        float x0 = ip[n * 3], x1 = ip[n * 3 + 1], x2 = ip[n * 3 + 2];
#pragma unroll
        for (int c = 0; c < 64; c++) {
            float z = x0 * W0[c] + x1 * W1[c] + x2 * W2[c] + Bv[c];
            float h = relu(z * S[c] + T[c]);
            mx[c] = fmaxf(mx[c], h);
        }
    }
#pragma unroll
    for (int c = 0; c < 64; c++) atomicMax(&smax[c], __float_as_uint(mx[c]));
    __syncthreads();
    if (tid < 64) xmax[b * 64 + tid] = __uint_as_float(smax[tid]);
}

// ---------------- K2: t-net stage 2 ----------------
__global__ __launch_bounds__(64) void k_tnet2(const float* __restrict__ xmax,
                                              const float* __restrict__ w1, const float* __restrict__ b1,
                                              const float* __restrict__ bn2p,
                                              const float* __restrict__ w2, const float* __restrict__ b2,
                                              float* __restrict__ transform) {
    int b = blockIdx.x, t = threadIdx.x;
    __shared__ float x2[64];
    const float* xm = xmax + b * 64;
    float acc = b1[t];
    for (int j = 0; j < 64; j++) acc += xm[j] * w1[j * 64 + t];
    float g = bn2p[t], be = bn2p[64 + t], m = bn2p[128 + t], v = bn2p[192 + t];
    float s = g * rsqrtf(v + EPSBN);
    x2[t] = relu(acc * s + (be - m * s));
    __syncthreads();
    if (t < 9) {
        float a = b2[t];
        for (int j = 0; j < 64; j++) a += x2[j] * w2[j * 9 + t];
        transform[b * 9 + t] = a;
    }
}

// ---------------- K3: pct = inputs @ transform ----------------
__global__ __launch_bounds__(256) void k_pct(const float* __restrict__ inp,
                                             const float* __restrict__ transform,
                                             float* __restrict__ pct) {
    int b = blockIdx.y;
    int n = blockIdx.x * 256 + threadIdx.x;
    __shared__ float T[9];
    if (threadIdx.x < 9) T[threadIdx.x] = transform[b * 9 + threadIdx.x];
    __syncthreads();
    const float* ip = inp + ((size_t)b * 2048 + n) * 3;
    float x0 = ip[0], x1 = ip[1], x2 = ip[2];
    float* op = pct + ((size_t)b * 2049 + n) * 3;
    op[0] = x0 * T[0] + x1 * T[3] + x2 * T[6];
    op[1] = x0 * T[1] + x1 * T[4] + x2 * T[7];
    op[2] = x0 * T[2] + x1 * T[5] + x2 * T[8];
}

// ---------------- K4: gather -> 96->128 -> 128->256 -> channel max ----------------
__global__ __launch_bounds__(256) void k_feat(const float* __restrict__ pct,
                                              const int* __restrict__ indices,
                                              const float* __restrict__ w1, const float* __restrict__ b1,
                                              const float* __restrict__ bn1p,
                                              const float* __restrict__ w2, const float* __restrict__ b2,
                                              const float* __restrict__ bn2p,
                                              u32* __restrict__ maxfeats) {
    int b = blockIdx.y, n0 = blockIdx.x * 32, tid = threadIdx.x;
    __shared__ float ft[96][36];    // gathered feats transposed [j][p]
    __shared__ float h1t[128][36];  // hidden1 transposed [c][p]
    __shared__ float S1[128], T1[128], Bi1[128], S2[256], T2[256], Bi2[256];

    if (tid < 128) {
        float g = bn1p[tid], be = bn1p[128 + tid], m = bn1p[256 + tid], v = bn1p[384 + tid];
        float s = g * rsqrtf(v + EPSBN);
        S1[tid] = s; T1[tid] = be - m * s; Bi1[tid] = b1[tid];
    }
    {
        int c = tid;
        float g = bn2p[c], be = bn2p[256 + c], m = bn2p[512 + c], v = bn2p[768 + c];
        float s = g * rsqrtf(v + EPSBN);
        S2[c] = s; T2[c] = be - m * s; Bi2[c] = b2[c];
    }
    {
        const float* pb = pct + (size_t)b * 2049 * 3;
        const int* ib = indices + ((size_t)b * 2048 + n0) * 32;
#pragma unroll
        for (int r = 0; r < 4; r++) {
            int i = tid + 256 * r;
            int p = i >> 5, k = i & 31;
            int idx = ib[p * 32 + k];
            const float* s = pb + (size_t)idx * 3;
            ft[3 * k + 0][p] = s[0];
            ft[3 * k + 1][p] = s[1];
            ft[3 * k + 2][p] = s[2];
        }
    }
    __syncthreads();
    // phase A: 96 -> 128, tiles 4p x 4c
    {
        int c0 = (tid & 31) * 4;
        int p0 = (tid >> 5) * 4;
        float acc[4][4];
#pragma unroll
        for (int i = 0; i < 4; i++)
#pragma unroll
            for (int j = 0; j < 4; j++) acc[i][j] = 0.f;
        for (int j = 0; j < 96; j++) {
            float4 f = *(const float4*)&ft[j][p0];
            float4 wv = *(const float4*)&w1[j * 128 + c0];
            acc[0][0] += f.x * wv.x; acc[0][1] += f.x * wv.y; acc[0][2] += f.x * wv.z; acc[0][3] += f.x * wv.w;
            acc[1][0] += f.y * wv.x; acc[1][1] += f.y * wv.y; acc[1][2] += f.y * wv.z; acc[1][3] += f.y * wv.w;
            acc[2][0] += f.z * wv.x; acc[2][1] += f.z * wv.y; acc[2][2] += f.z * wv.z; acc[2][3] += f.z * wv.w;
            acc[3][0] += f.w * wv.x; acc[3][1] += f.w * wv.y; acc[3][2] += f.w * wv.z; acc[3][3] += f.w * wv.w;
        }
#pragma unroll
        for (int cc = 0; cc < 4; cc++) {
            int c = c0 + cc;
            float bi = Bi1[c], s = S1[c], t = T1[c];
#pragma unroll
            for (int i = 0; i < 4; i++) h1t[c][p0 + i] = relu((acc[i][cc] + bi) * s + t);
        }
    }
    __syncthreads();
    // phase B: 128 -> 256, tiles 8p x 4c, then channel max
    {
        int c0 = (tid & 63) * 4;
        int p0 = (tid >> 6) * 8;
        float acc[8][4];
#pragma unroll
        for (int i = 0; i < 8; i++)
#pragma unroll
            for (int j = 0; j < 4; j++) acc[i][j] = 0.f;
        for (int k = 0; k < 128; k++) {
            float4 ha = *(const float4*)&h1t[k][p0];
            float4 hb = *(const float4*)&h1t[k][p0 + 4];
            float4 wv = *(const float4*)&w2[k * 256 + c0];
            acc[0][0] += ha.x * wv.x; acc[0][1] += ha.x * wv.y; acc[0][2] += ha.x * wv.z; acc[0][3] += ha.x * wv.w;
            acc[1][0] += ha.y * wv.x; acc[1][1] += ha.y * wv.y; acc[1][2] += ha.y * wv.z; acc[1][3] += ha.y * wv.w;
            acc[2][0] += ha.z * wv.x; acc[2][1] += ha.z * wv.y; acc[2][2] += ha.z * wv.z; acc[2][3] += ha.z * wv.w;
            acc[3][0] += ha.w * wv.x; acc[3][1] += ha.w * wv.y; acc[3][2] += ha.w * wv.z; acc[3][3] += ha.w * wv.w;
            acc[4][0] += hb.x * wv.x; acc[4][1] += hb.x * wv.y; acc[4][2] += hb.x * wv.z; acc[4][3] += hb.x * wv.w;
            acc[5][0] += hb.y * wv.x; acc[5][1] += hb.y * wv.y; acc[5][2] += hb.y * wv.z; acc[5][3] += hb.y * wv.w;
            acc[6][0] += hb.z * wv.x; acc[6][1] += hb.z * wv.y; acc[6][2] += hb.z * wv.z; acc[6][3] += hb.z * wv.w;
            acc[7][0] += hb.w * wv.x; acc[7][1] += hb.w * wv.y; acc[7][2] += hb.w * wv.z; acc[7][3] += hb.w * wv.w;
        }
        float mxv[4];
#pragma unroll
        for (int cc = 0; cc < 4; cc++) {
            int c = c0 + cc;
            float bi = Bi2[c], s = S2[c], t = T2[c];
            float m = 0.f;
#pragma unroll
            for (int i = 0; i < 8; i++) m = fmaxf(m, relu((acc[i][cc] + bi) * s + t));
            mxv[cc] = m;
        }
        float* red = &ft[0][0];  // alias (ft no longer read)
        int pg = tid >> 6;
#pragma unroll
        for (int cc = 0; cc < 4; cc++) red[pg * 256 + c0 + cc] = mxv[cc];
        __syncthreads();
        if (tid < 64) {
#pragma unroll
            for (int cc = 0; cc < 4; cc++) {
                int c = tid * 4 + cc;
                float m = fmaxf(fmaxf(red[c], red[256 + c]), fmaxf(red[512 + c], red[768 + c]));
                atomicMax(&maxfeats[b * 256 + c], __float_as_uint(m));
            }
        }
    }
}

// ---------------- K5: single g-row per batch -> pct row 2048 ----------------
__global__ __launch_bounds__(256) void k_gvec(const u32* __restrict__ maxfeats,
                                              const float* __restrict__ bn3p,
                                              const float* __restrict__ dw, const float* __restrict__ db,
                                              float* __restrict__ pct) {
    int b = blockIdx.x, c = threadIdx.x;
    __shared__ float red[3][256];
    float mf = __uint_as_float(maxfeats[b * 256 + c]);
    float g = bn3p[c], be = bn3p[256 + c], m = bn3p[512 + c], v = bn3p[768 + c];
    float s = g * rsqrtf(v + EPSBN);
    float y = mf * s + (be - m * s);  // no relu on bn3
    red[0][c] = y * dw[c * 3 + 0];
    red[1][c] = y * dw[c * 3 + 1];
    red[2][c] = y * dw[c * 3 + 2];
    __syncthreads();
    for (int st = 128; st > 0; st >>= 1) {
        if (c < st) {
            red[0][c] += red[0][c + st];
            red[1][c] += red[1][c + st];
            red[2][c] += red[2][c + st];
        }
        __syncthreads();
    }
    if (c < 3) pct[((size_t)b * 2049 + 2048) * 3 + c] = red[c][0] + db[c];
}

// ---------------- K6: 3->512->256->128 MLP + row max ----------------
__global__ __launch_bounds__(256) void k_mlp(const float* __restrict__ pct,
                                             const float* __restrict__ w3, const float* __restrict__ b3,
                                             const float* __restrict__ bn4p,
                                             const float* __restrict__ w4, const float* __restrict__ b4,
                                             const float* __restrict__ bn5p,
                                             const float* __restrict__ w5, const float* __restrict__ b5,
                                             const float* __restrict__ bn6p,
                                             u32* __restrict__ netmax) {
    __shared__ __align__(16) float LDSF[15424];
    float* h512t = LDSF;            // [512][20]
    float* h256t = LDSF + 10240;    // [256][20]
    float* rows = LDSF + 15360;     // [16][4]
    float* red = LDSF;              // [8][128] alias (phase 3 only)

    int b = blockIdx.y;
    int r0 = blockIdx.x * 16;
    int tid = threadIdx.x;
    int nrows = 2049 - r0; if (nrows > 16) nrows = 16;

    if (tid < 16) {
        float v0 = 0.f, v1 = 0.f, v2 = 0.f;
        if (tid < nrows) {
            const float* s = pct + ((size_t)b * 2049 + r0 + tid) * 3;
            v0 = s[0]; v1 = s[1]; v2 = s[2];
        }
        rows[tid * 4] = v0; rows[tid * 4 + 1] = v1; rows[tid * 4 + 2] = v2;
    }
    __syncthreads();
    // phase 1: 3 -> 512
#pragma unroll
    for (int half = 0; half < 2; half++) {
        int c = tid + half * 256;
        float w0 = w3[c], w1f = w3[512 + c], w2f = w3[1024 + c];
        float bi = b3[c];
        float g = bn4p[c], be = bn4p[512 + c], m = bn4p[1024 + c], v = bn4p[1536 + c];
        float s = g * rsqrtf(v + EPSBN), t = be - m * s;
#pragma unroll
        for (int p = 0; p < 16; p++) {
            float z = rows[p * 4] * w0 + rows[p * 4 + 1] * w1f + rows[p * 4 + 2] * w2f + bi;
            h512t[c * 20 + p] = relu(z * s + t);
        }
    }
    __syncthreads();
    // phase 2: 512 -> 256, tiles 4p x 4c
    {
        int c0 = (tid & 63) * 4;
        int p0 = (tid >> 6) * 4;
        float acc[4][4];
#pragma unroll
        for (int i = 0; i < 4; i++)
#pragma unroll
            for (int j = 0; j < 4; j++) acc[i][j] = 0.f;
        for (int k = 0; k < 512; k++) {
            float4 h = *(const float4*)&h512t[k * 20 + p0];
            float4 wv = *(const float4*)&w4[k * 256 + c0];
            acc[0][0] += h.x * wv.x; acc[0][1] += h.x * wv.y; acc[0][2] += h.x * wv.z; acc[0][3] += h.x * wv.w;
            acc[1][0] += h.y * wv.x; acc[1][1] += h.y * wv.y; acc[1][2] += h.y * wv.z; acc[1][3] += h.y * wv.w;
            acc[2][0] += h.z * wv.x; acc[2][1] += h.z * wv.y; acc[2][2] += h.z * wv.z; acc[2][3] += h.z * wv.w;
            acc[3][0] += h.w * wv.x; acc[3][1] += h.w * wv.y; acc[3][2] += h.w * wv.z; acc[3][3] += h.w * wv.w;
        }
#pragma unroll
        for (int cc = 0; cc < 4; cc++) {
            int c = c0 + cc;
            float bi = b4[c];
            float g = bn5p[c], be = bn5p[256 + c], m = bn5p[512 + c], v = bn5p[768 + c];
            float s = g * rsqrtf(v + EPSBN), t = be - m * s;
#pragma unroll
            for (int i = 0; i < 4; i++) h256t[c * 20 + p0 + i] = relu((acc[i][cc] + bi) * s + t);
        }
    }
    __syncthreads();
    // phase 3: 256 -> 128, tiles 2p x 4c, masked row max
    {
        int c0 = (tid & 31) * 4;
        int pg = tid >> 5;
        int p0 = pg * 2;
        float acc[2][4];
#pragma unroll
        for (int i = 0; i < 2; i++)
#pragma unroll
            for (int j = 0; j < 4; j++) acc[i][j] = 0.f;
        for (int k = 0; k < 256; k++) {
            float2 h = *(const float2*)&h256t[k * 20 + p0];
            float4 wv = *(const float4*)&w5[k * 128 + c0];
            acc[0][0] += h.x * wv.x; acc[0][1] += h.x * wv.y; acc[0][2] += h.x * wv.z; acc[0][3] += h.x * wv.w;
            acc[1][0] += h.y * wv.x; acc[1][1] += h.y * wv.y; acc[1][2] += h.y * wv.z; acc[1][3] += h.y * wv.w;
        }
        float mxv[4];
#pragma unroll
        for (int cc = 0; cc < 4; cc++) {
            int c = c0 + cc;
            float bi = b5[c];
            float g = bn6p[c], be = bn6p[128 + c], m = bn6p[256 + c], v = bn6p[384 + c];
            float s = g * rsqrtf(v + EPSBN), t = be - m * s;
            float mm = 0.f;
#pragma unroll
            for (int i = 0; i < 2; i++) {
                if (p0 + i < nrows) mm = fmaxf(mm, relu((acc[i][cc] + bi) * s + t));
            }
            mxv[cc] = mm;
        }
        __syncthreads();
#pragma unroll
        for (int cc = 0; cc < 4; cc++) red[pg * 128 + c0 + cc] = mxv[cc];
        __syncthreads();
        if (tid < 32) {
#pragma unroll
            for (int cc = 0; cc < 4; cc++) {
                int c = tid * 4 + cc;
                float m = red[c];
#pragma unroll
                for (int g2 = 1; g2 < 8; g2++) m = fmaxf(m, red[g2 * 128 + c]);
                atomicMax(&netmax[b * 128 + c], __float_as_uint(m));
            }
        }
    }
}

// ---------------- K7: final bn, dtype-aware store ----------------
__global__ __launch_bounds__(256) void k_out(const u32* __restrict__ netmax,
                                             const float* __restrict__ bng,
                                             const u32* __restrict__ flag,
                                             void* __restrict__ out) {
    int i = blockIdx.x * 256 + threadIdx.x;  // 4096
    int c = i & 127;
    float v = __uint_as_float(netmax[i]);
    float g = bng[c], be = bng[128 + c], m = bng[256 + c], va = bng[384 + c];
    float s = g * rsqrtf(va + EPSBN);
    float val = v * s + (be - m * s);
    if (flag[0]) ((u16*)out)[i] = f2bf(val);
    else ((float*)out)[i] = val;
}

extern "C" void kernel_launch(void* const* d_in, const int* in_sizes, int n_in,
                              void* d_out, int out_size, void* d_ws, size_t ws_size,
                              hipStream_t stream) {
    float* ws = (float*)d_ws;
    u32* flag = (u32*)ws;

    static const int order[28] = {0,2,3,4,5,6,7,8,9,10,11,12,13,14,15,16,17,18,19,20,21,22,23,24,25,26,27,28};
    static const int nels[28] = {196608,192,64,256,4096,64,256,576,9,12288,128,512,32768,256,1024,1024,768,3,1536,512,2048,131072,256,1024,32768,128,512,512};
    static const int offs[28] = {A_INPUTS,A_TC1W,A_TC1B,A_TBN1,A_TD1W,A_TD1B,A_TBN2,A_TD2W,A_TD2B,A_C1W,A_C1B,A_BN1,A_C2W,A_C2B,A_BN2,A_BN3,A_D1W,A_D1B,A_C3W,A_C3B,A_BN4,A_BLK1W,A_BLK1B,A_BLK1BN,A_BLK2W,A_BLK2B,A_BLK2BN,A_BNGF};
    ConvArgs ca;
    for (int i = 0; i < 28; i++) { ca.src[i] = d_in[order[i]]; ca.n[i] = nels[i]; ca.off[i] = offs[i]; }

    const int* indices = (const int*)d_in[1];

    k_detect<<<1, 64, 0, stream>>>((const u16*)d_in[4], flag);
    k_convert<<<dim3(32, 28), 256, 0, stream>>>(ca, ws, flag);

    // zero maxfeats + netmax
    hipMemsetAsync(ws + S_MAXF, 0, (size_t)12288 * 4, stream);

    k_tnet1<<<32, 256, 0, stream>>>(ws + A_INPUTS, ws + A_TC1W, ws + A_TC1B, ws + A_TBN1, ws + S_XMAX);
    k_tnet2<<<32, 64, 0, stream>>>(ws + S_XMAX, ws + A_TD1W, ws + A_TD1B, ws + A_TBN2, ws + A_TD2W, ws + A_TD2B, ws + S_TRF);
    k_pct<<<dim3(8, 32), 256, 0, stream>>>(ws + A_INPUTS, ws + S_TRF, ws + S_PCT);
    k_feat<<<dim3(64, 32), 256, 0, stream>>>(ws + S_PCT, indices,
                                             ws + A_C1W, ws + A_C1B, ws + A_BN1,
                                             ws + A_C2W, ws + A_C2B, ws + A_BN2,
                                             (u32*)(ws + S_MAXF));
    k_gvec<<<32, 256, 0, stream>>>((u32*)(ws + S_MAXF), ws + A_BN3, ws + A_D1W, ws + A_D1B, ws + S_PCT);
    k_mlp<<<dim3(129, 32), 256, 0, stream>>>(ws + S_PCT,
                                             ws + A_C3W, ws + A_C3B, ws + A_BN4,
                                             ws + A_BLK1W, ws + A_BLK1B, ws + A_BLK1BN,
                                             ws + A_BLK2W, ws + A_BLK2B, ws + A_BLK2BN,
                                             (u32*)(ws + S_NETMAX));
    k_out<<<16, 256, 0, stream>>>((u32*)(ws + S_NETMAX), ws + A_BNGF, flag, d_out);
}

// Round 3
// 408.341 us; speedup vs baseline: 1.9090x; 1.9090x over previous
//
#include <hip/hip_runtime.h>

typedef unsigned short u16;
typedef unsigned int u32;
typedef __attribute__((ext_vector_type(8))) short bf16x8;
typedef __attribute__((ext_vector_type(4))) float f32x4;

#define EPSBN 0.001f
#define MFMA16(a, b, c) __builtin_amdgcn_mfma_f32_16x16x32_bf16(a, b, c, 0, 0, 0)

__device__ __forceinline__ float bf2f(u16 u) {
    return __uint_as_float(((u32)u) << 16);
}
__device__ __forceinline__ u16 f2bf(float f) {
    u32 u = __float_as_uint(f);
    u32 r = u + 0x7FFFu + ((u >> 16) & 1u);
    return (u16)(r >> 16);
}
__device__ __forceinline__ float relu(float x) { return x > 0.f ? x : 0.f; }

// ---------------- ws layout (float offsets) ----------------
#define A_INPUTS 64       // 196608
#define A_TC1W  196672
#define A_TC1B  196864
#define A_TBN1  196928
#define A_TD1W  197184
#define A_TD1B  201280
#define A_TBN2  201344
#define A_TD2W  201600
#define A_TD2B  202176
#define A_C1W   202240    // 12288 (conv1_w 96x128)
#define A_C1B   214528
#define A_BN1   214656
#define A_C2W   215168    // 32768 (conv2_w 128x256)
#define A_C2B   247936
#define A_BN2   248192
#define A_BN3   249216
#define A_D1W   250240
#define A_D1B   251008
#define A_C3W   251072    // 1536 (conv3_w 3x512)
#define A_C3B   252608
#define A_BN4   253120
#define A_BLK1W 255168    // 131072 (blk1_w 512x256)
#define A_BLK1B 386240
#define A_BLK1BN 386496
#define A_BLK2W 387520    // 32768 (blk2_w 256x128)
#define A_BLK2B 420288
#define A_BLK2BN 420416
#define A_BNGF  420928
#define S_XMAX  421440
#define S_TRF   423488
#define S_PCT   423808    // 196704 (32*2049*3 f32)
#define S_MAXF  620544    // 8192 u32
#define S_NETMAX 628736   // 4096 u32
// bf16 transposed weight arenas (u16 stored in float space)
#define T_C1WT  632832    // 128x96  u16 = 6144 floats
#define T_C2WT  638976    // 256x128 u16 = 16384 floats
#define T_W4T   655360    // 256x512 u16 = 65536 floats
#define T_W5T   720896    // 128x256 u16 = 16384 floats
// end 737280 floats = 2.95 MB

struct ConvArgs {
    const void* src[28];
    int n[28];
    int off[28];
};

// ---------------- detect: bf16 vs f32 inputs ----------------
__global__ __launch_bounds__(64) void k_detect(const u16* __restrict__ tbn1, u32* __restrict__ flag) {
    if (threadIdx.x == 0) {
        int ok = 1;
        for (int i = 0; i < 16; i += 2) {
            u16 v = tbn1[i];  // gamma ~ 1.0 +- 0.1 if bf16
            if (v < 0x3E00u || v > 0x4080u) ok = 0;
        }
        flag[0] = ok ? 1u : 0u;
    }
}

// ---------------- convert all float tensors to f32 arena ----------------
__global__ __launch_bounds__(256) void k_convert(ConvArgs a, float* __restrict__ ws, const u32* __restrict__ flag) {
    int t = blockIdx.y;
    int n = a.n[t];
    int cpb = (n + 31) >> 5;
    int s = blockIdx.x * cpb;
    int e = s + cpb; if (e > n) e = n;
    int isbf = (int)flag[0];
    float* dst = ws + a.off[t];
    if (isbf) {
        const u16* src = (const u16*)a.src[t];
        for (int i = s + (int)threadIdx.x; i < e; i += 256) dst[i] = bf2f(src[i]);
    } else {
        const float* src = (const float*)a.src[t];
        for (int i = s + (int)threadIdx.x; i < e; i += 256) dst[i] = src[i];
    }
}

// ---------------- prep: bf16 transposed weights  dst[c*K+k] = src[k*N+c] ----------------
__global__ __launch_bounds__(256) void k_prepw(const float* __restrict__ src, u16* __restrict__ dst,
                                               int K, int logN) {
    int i = blockIdx.x * 256 + threadIdx.x;
    int N1 = (1 << logN) - 1;
    int k = i >> logN, c = i & N1;
    dst[c * K + k] = f2bf(src[i]);
}

// ---------------- K1: t-net stage 1 ----------------
__global__ __launch_bounds__(256) void k_tnet1(const float* __restrict__ inp,
                                               const float* __restrict__ w,
                                               const float* __restrict__ bias,
                                               const float* __restrict__ bn,
                                               float* __restrict__ xmax) {
    int b = blockIdx.x;
    int tid = threadIdx.x;
    __shared__ float W0[64], W1[64], W2[64], S[64], T[64], Bv[64];
    __shared__ u32 smax[64];
    if (tid < 64) {
        W0[tid] = w[tid];
        W1[tid] = w[64 + tid];
        W2[tid] = w[128 + tid];
        float g = bn[tid], be = bn[64 + tid], m = bn[128 + tid], v = bn[192 + tid];
        float s = g * rsqrtf(v + EPSBN);
        S[tid] = s; T[tid] = be - m * s;
        Bv[tid] = bias[tid];
        smax[tid] = 0u;
    }
    __syncthreads();
    float mx[64];
#pragma unroll
    for (int c = 0; c < 64; c++) mx[c] = 0.f;
    const float* ip = inp + (size_t)b * 2048 * 3;
    for (int n = tid; n < 2048; n += 256) {
        float x0 = ip[n * 3], x1 = ip[n * 3 + 1], x2 = ip[n * 3 + 2];
#pragma unroll
        for (int c = 0; c < 64; c++) {
            float z = x0 * W0[c] + x1 * W1[c] + x2 * W2[c] + Bv[c];
            float h = relu(z * S[c] + T[c]);
            mx[c] = fmaxf(mx[c], h);
        }
    }
#pragma unroll
    for (int c = 0; c < 64; c++) atomicMax(&smax[c], __float_as_uint(mx[c]));
    __syncthreads();
    if (tid < 64) xmax[b * 64 + tid] = __uint_as_float(smax[tid]);
}

// ---------------- K2: t-net stage 2 ----------------
__global__ __launch_bounds__(64) void k_tnet2(const float* __restrict__ xmax,
                                              const float* __restrict__ w1, const float* __restrict__ b1,
                                              const float* __restrict__ bn2p,
                                              const float* __restrict__ w2, const float* __restrict__ b2,
                                              float* __restrict__ transform) {
    int b = blockIdx.x, t = threadIdx.x;
    __shared__ float x2[64];
    const float* xm = xmax + b * 64;
    float acc = b1[t];
    for (int j = 0; j < 64; j++) acc += xm[j] * w1[j * 64 + t];
    float g = bn2p[t], be = bn2p[64 + t], m = bn2p[128 + t], v = bn2p[192 + t];
    float s = g * rsqrtf(v + EPSBN);
    x2[t] = relu(acc * s + (be - m * s));
    __syncthreads();
    if (t < 9) {
        float a = b2[t];
        for (int j = 0; j < 64; j++) a += x2[j] * w2[j * 9 + t];
        transform[b * 9 + t] = a;
    }
}

// ---------------- K3: pct = inputs @ transform ----------------
__global__ __launch_bounds__(256) void k_pct(const float* __restrict__ inp,
                                             const float* __restrict__ transform,
                                             float* __restrict__ pct) {
    int b = blockIdx.y;
    int n = blockIdx.x * 256 + threadIdx.x;
    __shared__ float T[9];
    if (threadIdx.x < 9) T[threadIdx.x] = transform[b * 9 + threadIdx.x];
    __syncthreads();
    const float* ip = inp + ((size_t)b * 2048 + n) * 3;
    float x0 = ip[0], x1 = ip[1], x2 = ip[2];
    float* op = pct + ((size_t)b * 2049 + n) * 3;
    op[0] = x0 * T[0] + x1 * T[3] + x2 * T[6];
    op[1] = x0 * T[1] + x1 * T[4] + x2 * T[7];
    op[2] = x0 * T[2] + x1 * T[5] + x2 * T[8];
}

// ---------------- K4: MFMA gather -> 96->128 -> 128->256 -> channel max ----------------
__global__ __launch_bounds__(256) void k_feat(const float* __restrict__ pct,
                                              const int* __restrict__ indices,
                                              const u16* __restrict__ w1t, const float* __restrict__ b1,
                                              const float* __restrict__ bn1p,
                                              const u16* __restrict__ w2t, const float* __restrict__ b2,
                                              const float* __restrict__ bn2p,
                                              u32* __restrict__ maxfeats) {
    __shared__ __align__(16) u16 ftA[4096];   // [32 pts][128] bf16, pitch 256B, swizzled (96 used)
    __shared__ __align__(16) u16 h1B[4096];   // [32][128] bf16, pitch 256B, swizzled
    __shared__ float sB1[128], sS1[128], sT1[128];
    __shared__ float sB2[256], sS2[256], sT2[256];

    int b = blockIdx.y, n0p = blockIdx.x * 32, tid = threadIdx.x;
    if (tid < 128) {
        float g = bn1p[tid], be = bn1p[128 + tid], m = bn1p[256 + tid], v = bn1p[384 + tid];
        float s = g * rsqrtf(v + EPSBN);
        sS1[tid] = s; sT1[tid] = be - m * s; sB1[tid] = b1[tid];
    }
    {
        int c = tid;
        float g = bn2p[c], be = bn2p[256 + c], m = bn2p[512 + c], v = bn2p[768 + c];
        float s = g * rsqrtf(v + EPSBN);
        sS2[c] = s; sT2[c] = be - m * s; sB2[c] = b2[c];
    }
    // gather 32 pts x 32 neighbors x 3 -> ftA bf16 swizzled
    {
        const float* pb = pct + (size_t)b * 2049 * 3;
        const int* ib = indices + ((size_t)b * 2048 + n0p) * 32;
        char* fA = (char*)ftA;
#pragma unroll
        for (int r = 0; r < 4; r++) {
            int i = tid + 256 * r;
            int p = i >> 5, k = i & 31;
            int idx = ib[p * 32 + k];
            const float* s = pb + (size_t)idx * 3;
            int sw = (p & 7) << 4;
            int base = p * 256 + 6 * k;
            *(u16*)(fA + ((base) ^ sw)) = f2bf(s[0]);
            *(u16*)(fA + ((base + 2) ^ sw)) = f2bf(s[1]);
            *(u16*)(fA + ((base + 4) ^ sw)) = f2bf(s[2]);
        }
    }
    __syncthreads();

    int lane = tid & 63, wv = tid >> 6;
    int rw = lane & 15, kq = lane >> 4;
    int axor = (rw & 7) << 4;

    // GEMM A: [32][96] x W1T[128][96]
    {
        f32x4 acc[2][2];
#pragma unroll
        for (int m = 0; m < 2; m++)
#pragma unroll
            for (int n = 0; n < 2; n++) acc[m][n] = (f32x4){0.f, 0.f, 0.f, 0.f};
        const char* fA = (const char*)ftA;
        const char* W = (const char*)w1t;
        int nb = wv * 32;
#pragma unroll
        for (int ks = 0; ks < 3; ks++) {
            bf16x8 a0 = *(const bf16x8*)(fA + ((rw * 256 + ks * 64 + kq * 16) ^ axor));
            bf16x8 a1 = *(const bf16x8*)(fA + (((rw + 16) * 256 + ks * 64 + kq * 16) ^ axor));
            bf16x8 b0 = *(const bf16x8*)(W + ((nb + rw) * 192 + ks * 64 + kq * 16));
            bf16x8 b1v = *(const bf16x8*)(W + ((nb + 16 + rw) * 192 + ks * 64 + kq * 16));
            acc[0][0] = MFMA16(a0, b0, acc[0][0]);
            acc[1][0] = MFMA16(a1, b0, acc[1][0]);
            acc[0][1] = MFMA16(a0, b1v, acc[0][1]);
            acc[1][1] = MFMA16(a1, b1v, acc[1][1]);
        }
        char* hB = (char*)h1B;
#pragma unroll
        for (int nt = 0; nt < 2; nt++) {
            int c = nb + nt * 16 + rw;
            float s = sS1[c], t = sT1[c], bi = sB1[c];
#pragma unroll
            for (int m = 0; m < 2; m++)
#pragma unroll
                for (int r = 0; r < 4; r++) {
                    int rr = m * 16 + kq * 4 + r;
                    float h = relu((acc[m][nt][r] + bi) * s + t);
                    *(u16*)(hB + ((rr * 256 + c * 2) ^ ((rr & 7) << 4))) = f2bf(h);
                }
        }
    }
    __syncthreads();
    // GEMM B: [32][128] x W2T[256][128], then channel max
    {
        f32x4 acc[2][4];
#pragma unroll
        for (int m = 0; m < 2; m++)
#pragma unroll
            for (int n = 0; n < 4; n++) acc[m][n] = (f32x4){0.f, 0.f, 0.f, 0.f};
        const char* hB = (const char*)h1B;
        const char* W = (const char*)w2t;
        int nb = wv * 64;
#pragma unroll
        for (int ks = 0; ks < 4; ks++) {
            bf16x8 a0 = *(const bf16x8*)(hB + ((rw * 256 + ks * 64 + kq * 16) ^ axor));
            bf16x8 a1 = *(const bf16x8*)(hB + (((rw + 16) * 256 + ks * 64 + kq * 16) ^ axor));
#pragma unroll
            for (int nt = 0; nt < 4; nt++) {
                bf16x8 bv = *(const bf16x8*)(W + ((nb + nt * 16 + rw) * 256 + ks * 64 + kq * 16));
                acc[0][nt] = MFMA16(a0, bv, acc[0][nt]);
                acc[1][nt] = MFMA16(a1, bv, acc[1][nt]);
            }
        }
#pragma unroll
        for (int nt = 0; nt < 4; nt++) {
            int c = nb + nt * 16 + rw;
            float s = sS2[c], t = sT2[c], bi = sB2[c];
            float vm = 0.f;
#pragma unroll
            for (int m = 0; m < 2; m++)
#pragma unroll
                for (int r = 0; r < 4; r++)
                    vm = fmaxf(vm, relu((acc[m][nt][r] + bi) * s + t));
            vm = fmaxf(vm, __shfl_xor(vm, 16));
            vm = fmaxf(vm, __shfl_xor(vm, 32));
            if (kq == 0) atomicMax(&maxfeats[b * 256 + c], __float_as_uint(vm));
        }
    }
}

// ---------------- K5: single g-row per batch -> pct row 2048 ----------------
__global__ __launch_bounds__(256) void k_gvec(const u32* __restrict__ maxfeats,
                                              const float* __restrict__ bn3p,
                                              const float* __restrict__ dw, const float* __restrict__ db,
                                              float* __restrict__ pct) {
    int b = blockIdx.x, c = threadIdx.x;
    __shared__ float red[3][256];
    float mf = __uint_as_float(maxfeats[b * 256 + c]);
    float g = bn3p[c], be = bn3p[256 + c], m = bn3p[512 + c], v = bn3p[768 + c];
    float s = g * rsqrtf(v + EPSBN);
    float y = mf * s + (be - m * s);
    red[0][c] = y * dw[c * 3 + 0];
    red[1][c] = y * dw[c * 3 + 1];
    red[2][c] = y * dw[c * 3 + 2];
    __syncthreads();
    for (int st = 128; st > 0; st >>= 1) {
        if (c < st) {
            red[0][c] += red[0][c + st];
            red[1][c] += red[1][c + st];
            red[2][c] += red[2][c + st];
        }
        __syncthreads();
    }
    if (c < 3) pct[((size_t)b * 2049 + 2048) * 3 + c] = red[c][0] + db[c];
}

// ---------------- K6: MFMA 3->512->256->128 + row max ----------------
__global__ __launch_bounds__(256) void k_mlp(const float* __restrict__ pct,
                                             const float* __restrict__ w3, const float* __restrict__ b3,
                                             const float* __restrict__ bn4p,
                                             const u16* __restrict__ w4t, const float* __restrict__ b4f,
                                             const float* __restrict__ bn5p,
                                             const u16* __restrict__ w5t, const float* __restrict__ b5f,
                                             const float* __restrict__ bn6p,
                                             u32* __restrict__ netmax) {
    __shared__ __align__(16) u16 hA[16384];  // [32][512] bf16 pitch 1024B swizzled
    __shared__ __align__(16) u16 hB[8192];   // [32][256] bf16 pitch 512B swizzled
    __shared__ float rowsS[128];
    __shared__ float sB4[256], sS5[256], sT5[256];
    __shared__ float sB5[128], sS6[128], sT6[128];

    int b = blockIdx.y, r0 = blockIdx.x * 32, tid = threadIdx.x;
    int nrows = 2049 - r0; if (nrows > 32) nrows = 32;

    {
        int c = tid;
        float g = bn5p[c], be = bn5p[256 + c], m = bn5p[512 + c], v = bn5p[768 + c];
        float s = g * rsqrtf(v + EPSBN);
        sS5[c] = s; sT5[c] = be - m * s; sB4[c] = b4f[c];
    }
    if (tid < 128) {
        int c = tid;
        float g = bn6p[c], be = bn6p[128 + c], m = bn6p[256 + c], v = bn6p[384 + c];
        float s = g * rsqrtf(v + EPSBN);
        sS6[c] = s; sT6[c] = be - m * s; sB5[c] = b5f[c];
    }
    if (tid < 32) {
        float v0 = 0.f, v1 = 0.f, v2 = 0.f;
        if (tid < nrows) {
            const float* s = pct + ((size_t)b * 2049 + r0 + tid) * 3;
            v0 = s[0]; v1 = s[1]; v2 = s[2];
        }
        rowsS[tid * 4] = v0; rowsS[tid * 4 + 1] = v1; rowsS[tid * 4 + 2] = v2;
    }
    __syncthreads();
    // phase 1: 3 -> 512 (VALU), write hA bf16 swizzled
    {
        char* hAc = (char*)hA;
#pragma unroll
        for (int half = 0; half < 2; half++) {
            int c = tid + half * 256;
            float w0 = w3[c], w1f = w3[512 + c], w2f = w3[1024 + c];
            float bi = b3[c];
            float g = bn4p[c], be = bn4p[512 + c], m = bn4p[1024 + c], v = bn4p[1536 + c];
            float s = g * rsqrtf(v + EPSBN), t = be - m * s;
#pragma unroll
            for (int p = 0; p < 32; p++) {
                float z = rowsS[p * 4] * w0 + rowsS[p * 4 + 1] * w1f + rowsS[p * 4 + 2] * w2f + bi;
                float h = relu(z * s + t);
                *(u16*)(hAc + ((p * 1024 + c * 2) ^ ((p & 7) << 4))) = f2bf(h);
            }
        }
    }
    __syncthreads();

    int lane = tid & 63, wv = tid >> 6;
    int rw = lane & 15, kq = lane >> 4;
    int axor = (rw & 7) << 4;

    // phase 2: [32][512] x W4T[256][512] -> hB
    {
        f32x4 acc[2][4];
#pragma unroll
        for (int m = 0; m < 2; m++)
#pragma unroll
            for (int n = 0; n < 4; n++) acc[m][n] = (f32x4){0.f, 0.f, 0.f, 0.f};
        const char* A = (const char*)hA;
        const char* W = (const char*)w4t;
        int nb = wv * 64;
        auto lA = [&](int m, int ks) -> bf16x8 {
            return *(const bf16x8*)(A + (((rw + m) * 1024 + ks * 64 + kq * 16) ^ axor));
        };
        auto lB = [&](int nt, int ks) -> bf16x8 {
            return *(const bf16x8*)(W + ((nb + nt * 16 + rw) * 1024 + ks * 64 + kq * 16));
        };
        bf16x8 a0 = lA(0, 0), a1 = lA(16, 0);
        bf16x8 b0 = lB(0, 0), b1v = lB(1, 0), b2v = lB(2, 0), b3v = lB(3, 0);
#pragma unroll
        for (int ks = 0; ks < 16; ks++) {
            bf16x8 na0, na1, nb0, nb1, nb2, nb3;
            if (ks < 15) {
                na0 = lA(0, ks + 1); na1 = lA(16, ks + 1);
                nb0 = lB(0, ks + 1); nb1 = lB(1, ks + 1); nb2 = lB(2, ks + 1); nb3 = lB(3, ks + 1);
            }
            acc[0][0] = MFMA16(a0, b0, acc[0][0]);  acc[1][0] = MFMA16(a1, b0, acc[1][0]);
            acc[0][1] = MFMA16(a0, b1v, acc[0][1]); acc[1][1] = MFMA16(a1, b1v, acc[1][1]);
            acc[0][2] = MFMA16(a0, b2v, acc[0][2]); acc[1][2] = MFMA16(a1, b2v, acc[1][2]);
            acc[0][3] = MFMA16(a0, b3v, acc[0][3]); acc[1][3] = MFMA16(a1, b3v, acc[1][3]);
            if (ks < 15) { a0 = na0; a1 = na1; b0 = nb0; b1v = nb1; b2v = nb2; b3v = nb3; }
        }
        char* HB = (char*)hB;
#pragma unroll
        for (int nt = 0; nt < 4; nt++) {
            int c = nb + nt * 16 + rw;
            float s = sS5[c], t = sT5[c], bi = sB4[c];
#pragma unroll
            for (int m = 0; m < 2; m++)
#pragma unroll
                for (int r = 0; r < 4; r++) {
                    int rr = m * 16 + kq * 4 + r;
                    float h = relu((acc[m][nt][r] + bi) * s + t);
                    *(u16*)(HB + ((rr * 512 + c * 2) ^ ((rr & 7) << 4))) = f2bf(h);
                }
        }
    }
    __syncthreads();
    // phase 3: [32][256] x W5T[128][256], masked row-max, atomic
    {
        f32x4 acc[2][2];
#pragma unroll
        for (int m = 0; m < 2; m++)
#pragma unroll
            for (int n = 0; n < 2; n++) acc[m][n] = (f32x4){0.f, 0.f, 0.f, 0.f};
        const char* A = (const char*)hB;
        const char* W = (const char*)w5t;
        int nb = wv * 32;
#pragma unroll
        for (int ks = 0; ks < 8; ks++) {
            bf16x8 a0 = *(const bf16x8*)(A + ((rw * 512 + ks * 64 + kq * 16) ^ axor));
            bf16x8 a1 = *(const bf16x8*)(A + (((rw + 16) * 512 + ks * 64 + kq * 16) ^ axor));
            bf16x8 w0 = *(const bf16x8*)(W + ((nb + rw) * 512 + ks * 64 + kq * 16));
            bf16x8 w1v = *(const bf16x8*)(W + ((nb + 16 + rw) * 512 + ks * 64 + kq * 16));
            acc[0][0] = MFMA16(a0, w0, acc[0][0]);
            acc[1][0] = MFMA16(a1, w0, acc[1][0]);
            acc[0][1] = MFMA16(a0, w1v, acc[0][1]);
            acc[1][1] = MFMA16(a1, w1v, acc[1][1]);
        }
#pragma unroll
        for (int nt = 0; nt < 2; nt++) {
            int c = nb + nt * 16 + rw;
            float s = sS6[c], t = sT6[c], bi = sB5[c];
            float vm = 0.f;
#pragma unroll
            for (int m = 0; m < 2; m++)
#pragma unroll
                for (int r = 0; r < 4; r++) {
                    int rr = m * 16 + kq * 4 + r;
                    float h = relu((acc[m][nt][r] + bi) * s + t);
                    if (rr < nrows) vm = fmaxf(vm, h);
                }
            vm = fmaxf(vm, __shfl_xor(vm, 16));
            vm = fmaxf(vm, __shfl_xor(vm, 32));
            if (kq == 0) atomicMax(&netmax[b * 128 + c], __float_as_uint(vm));
        }
    }
}

// ---------------- K7: final bn, dtype-aware store ----------------
__global__ __launch_bounds__(256) void k_out(const u32* __restrict__ netmax,
                                             const float* __restrict__ bng,
                                             const u32* __restrict__ flag,
                                             void* __restrict__ out) {
    int i = blockIdx.x * 256 + threadIdx.x;  // 4096
    int c = i & 127;
    float v = __uint_as_float(netmax[i]);
    float g = bng[c], be = bng[128 + c], m = bng[256 + c], va = bng[384 + c];
    float s = g * rsqrtf(va + EPSBN);
    float val = v * s + (be - m * s);
    if (flag[0]) ((u16*)out)[i] = f2bf(val);
    else ((float*)out)[i] = val;
}

extern "C" void kernel_launch(void* const* d_in, const int* in_sizes, int n_in,
                              void* d_out, int out_size, void* d_ws, size_t ws_size,
                              hipStream_t stream) {
    float* ws = (float*)d_ws;
    u32* flag = (u32*)ws;

    static const int order[28] = {0,2,3,4,5,6,7,8,9,10,11,12,13,14,15,16,17,18,19,20,21,22,23,24,25,26,27,28};
    static const int nels[28] = {196608,192,64,256,4096,64,256,576,9,12288,128,512,32768,256,1024,1024,768,3,1536,512,2048,131072,256,1024,32768,128,512,512};
    static const int offs[28] = {A_INPUTS,A_TC1W,A_TC1B,A_TBN1,A_TD1W,A_TD1B,A_TBN2,A_TD2W,A_TD2B,A_C1W,A_C1B,A_BN1,A_C2W,A_C2B,A_BN2,A_BN3,A_D1W,A_D1B,A_C3W,A_C3B,A_BN4,A_BLK1W,A_BLK1B,A_BLK1BN,A_BLK2W,A_BLK2B,A_BLK2BN,A_BNGF};
    ConvArgs ca;
    for (int i = 0; i < 28; i++) { ca.src[i] = d_in[order[i]]; ca.n[i] = nels[i]; ca.off[i] = offs[i]; }

    const int* indices = (const int*)d_in[1];

    k_detect<<<1, 64, 0, stream>>>((const u16*)d_in[4], flag);
    k_convert<<<dim3(32, 28), 256, 0, stream>>>(ca, ws, flag);

    // bf16 transposed weights
    k_prepw<<<48, 256, 0, stream>>>(ws + A_C1W, (u16*)(ws + T_C1WT), 96, 7);
    k_prepw<<<128, 256, 0, stream>>>(ws + A_C2W, (u16*)(ws + T_C2WT), 128, 8);
    k_prepw<<<512, 256, 0, stream>>>(ws + A_BLK1W, (u16*)(ws + T_W4T), 512, 8);
    k_prepw<<<128, 256, 0, stream>>>(ws + A_BLK2W, (u16*)(ws + T_W5T), 256, 7);

    // zero maxfeats + netmax
    hipMemsetAsync(ws + S_MAXF, 0, (size_t)12288 * 4, stream);

    k_tnet1<<<32, 256, 0, stream>>>(ws + A_INPUTS, ws + A_TC1W, ws + A_TC1B, ws + A_TBN1, ws + S_XMAX);
    k_tnet2<<<32, 64, 0, stream>>>(ws + S_XMAX, ws + A_TD1W, ws + A_TD1B, ws + A_TBN2, ws + A_TD2W, ws + A_TD2B, ws + S_TRF);
    k_pct<<<dim3(8, 32), 256, 0, stream>>>(ws + A_INPUTS, ws + S_TRF, ws + S_PCT);
    k_feat<<<dim3(64, 32), 256, 0, stream>>>(ws + S_PCT, indices,
                                             (const u16*)(ws + T_C1WT), ws + A_C1B, ws + A_BN1,
                                             (const u16*)(ws + T_C2WT), ws + A_C2B, ws + A_BN2,
                                             (u32*)(ws + S_MAXF));
    k_gvec<<<32, 256, 0, stream>>>((u32*)(ws + S_MAXF), ws + A_BN3, ws + A_D1W, ws + A_D1B, ws + S_PCT);
    k_mlp<<<dim3(65, 32), 256, 0, stream>>>(ws + S_PCT,
                                            ws + A_C3W, ws + A_C3B, ws + A_BN4,
                                            (const u16*)(ws + T_W4T), ws + A_BLK1B, ws + A_BLK1BN,
                                            (const u16*)(ws + T_W5T), ws + A_BLK2B, ws + A_BLK2BN,
                                            (u32*)(ws + S_NETMAX));
    k_out<<<16, 256, 0, stream>>>((u32*)(ws + S_NETMAX), ws + A_BNGF, flag, d_out);
}

// Round 4
// 271.157 us; speedup vs baseline: 2.8748x; 1.5059x over previous
//
#include <hip/hip_runtime.h>

typedef unsigned short u16;
typedef unsigned int u32;
typedef __attribute__((ext_vector_type(8))) short bf16x8;
typedef __attribute__((ext_vector_type(4))) float f32x4;

#define EPSBN 0.001f
#define MFMA16(a, b, c) __builtin_amdgcn_mfma_f32_16x16x32_bf16(a, b, c, 0, 0, 0)

__device__ __forceinline__ float bf2f(u16 u) {
    return __uint_as_float(((u32)u) << 16);
}
__device__ __forceinline__ u16 f2bf(float f) {
    u32 u = __float_as_uint(f);
    u32 r = u + 0x7FFFu + ((u >> 16) & 1u);
    return (u16)(r >> 16);
}
__device__ __forceinline__ float relu(float x) { return x > 0.f ? x : 0.f; }

// ---------------- ws layout (float offsets) ----------------
#define A_INPUTS 64       // 196608
#define A_TC1W  196672
#define A_TC1B  196864
#define A_TBN1  196928
#define A_TD1W  197184
#define A_TD1B  201280
#define A_TBN2  201344
#define A_TD2W  201600
#define A_TD2B  202176
#define A_C1W   202240    // 12288 (conv1_w 96x128)
#define A_C1B   214528
#define A_BN1   214656
#define A_C2W   215168    // 32768 (conv2_w 128x256)
#define A_C2B   247936
#define A_BN2   248192
#define A_BN3   249216
#define A_D1W   250240
#define A_D1B   251008
#define A_C3W   251072    // 1536 (conv3_w 3x512)
#define A_C3B   252608
#define A_BN4   253120
#define A_BLK1W 255168    // 131072 (blk1_w 512x256)
#define A_BLK1B 386240
#define A_BLK1BN 386496
#define A_BLK2W 387520    // 32768 (blk2_w 256x128)
#define A_BLK2B 420288
#define A_BLK2BN 420416
#define A_BNGF  420928
#define S_TRF   423488
#define S_PCT   423808    // 196704 (32*2049*3 f32)
// zeroed region: [S_MAXF, S_XMAX+2048) = 14336 floats
#define S_MAXF  620544    // 8192 u32
#define S_NETMAX 628736   // 4096 u32
#define S_XMAX  632832    // 2048 u32
// bf16 transposed weight arenas (u16 stored in float space)
#define T_C1WT  634880    // 128x96  u16 = 6144 floats
#define T_C2WT  641024    // 256x128 u16 = 16384 floats
#define T_W4T   657408    // 256x512 u16 = 65536 floats
#define T_W5T   722944    // 128x256 u16 = 16384 floats
// end 739328 floats = 2.96 MB

struct ConvArgs {
    const void* src[28];
    int n[28];
    int off[28];
};

struct PrepArgs {
    const float* src[4];
    u16* dst[4];
    int K[4];
    int logN[4];
    int base[4];
};

// ---------------- convert all float tensors to f32 arena (+inline dtype detect) ----------------
__global__ __launch_bounds__(256) void k_convert(ConvArgs a, const u16* __restrict__ tbn1,
                                                 float* __restrict__ ws, u32* __restrict__ flag) {
    // local dtype detect: gamma of t_bn1 ~ 1.0 +- 0.1 if bf16
    int ok = 1;
    for (int i = 0; i < 16; i += 2) {
        u16 v = tbn1[i];
        if (v < 0x3E00u || v > 0x4080u) ok = 0;
    }
    if (blockIdx.x == 0 && blockIdx.y == 0 && threadIdx.x == 0) flag[0] = ok ? 1u : 0u;

    int t = blockIdx.y;
    int n = a.n[t];
    int cpb = (n + 31) >> 5;
    int s = blockIdx.x * cpb;
    int e = s + cpb; if (e > n) e = n;
    float* dst = ws + a.off[t];
    if (ok) {
        const u16* src = (const u16*)a.src[t];
        for (int i = s + (int)threadIdx.x; i < e; i += 256) dst[i] = bf2f(src[i]);
    } else {
        const float* src = (const float*)a.src[t];
        for (int i = s + (int)threadIdx.x; i < e; i += 256) dst[i] = src[i];
    }
}

// ---------------- prep: bf16 transposed weights  dst[c*K+k] = src[k*N+c] (4 tensors, 1 launch) ----------------
__global__ __launch_bounds__(256) void k_prepw_all(PrepArgs pa) {
    int blk = blockIdx.x;
    int t = (blk < 48) ? 0 : (blk < 176) ? 1 : (blk < 688) ? 2 : 3;
    int i = (blk - pa.base[t]) * 256 + (int)threadIdx.x;
    int N1 = (1 << pa.logN[t]) - 1;
    int k = i >> pa.logN[t], c = i & N1;
    pa.dst[t][c * pa.K[t] + k] = f2bf(pa.src[t][i]);
}

// ---------------- K1: t-net stage 1: per-channel threads, broadcast LDS points ----------------
// grid (4 slices, 32 batches), 256 thr = 4 point-groups x 64 channels
__global__ __launch_bounds__(256) void k_tnet1(const float* __restrict__ inp,
                                               const float* __restrict__ w,
                                               const float* __restrict__ bias,
                                               const float* __restrict__ bn,
                                               u32* __restrict__ xmax) {
    __shared__ float pts[1536];    // 512 points x 3
    __shared__ float wred[4][64];
    int b = blockIdx.y, slice = blockIdx.x, tid = threadIdx.x;
    const float* ip = inp + ((size_t)b * 2048 + slice * 512) * 3;
#pragma unroll
    for (int i = 0; i < 6; i++) pts[tid + i * 256] = ip[tid + i * 256];

    int c = tid & 63, np = tid >> 6;
    float w0 = w[c], w1 = w[64 + c], w2 = w[128 + c], bi = bias[c];
    float g = bn[c], be = bn[64 + c], m = bn[128 + c], v = bn[192 + c];
    float s = g * rsqrtf(v + EPSBN), t = be - m * s;
    __syncthreads();

    float vmax = 0.f;  // relu >= 0
    int pbase = np * 128;
#pragma unroll 4
    for (int p = 0; p < 128; p++) {
        float x0 = pts[(pbase + p) * 3], x1 = pts[(pbase + p) * 3 + 1], x2 = pts[(pbase + p) * 3 + 2];
        float z = x0 * w0 + x1 * w1 + x2 * w2 + bi;
        vmax = fmaxf(vmax, z * s + t);
    }
    wred[np][c] = vmax;
    __syncthreads();
    if (tid < 64) {
        float mm = fmaxf(fmaxf(wred[0][tid], wred[1][tid]), fmaxf(wred[2][tid], wred[3][tid]));
        atomicMax(&xmax[b * 64 + tid], __float_as_uint(relu(mm)));
    }
}

// ---------------- K2: t-net stage 2 ----------------
__global__ __launch_bounds__(64) void k_tnet2(const float* __restrict__ xmax,
                                              const float* __restrict__ w1, const float* __restrict__ b1,
                                              const float* __restrict__ bn2p,
                                              const float* __restrict__ w2, const float* __restrict__ b2,
                                              float* __restrict__ transform) {
    int b = blockIdx.x, t = threadIdx.x;
    __shared__ float x2[64];
    const float* xm = xmax + b * 64;
    float acc = b1[t];
    for (int j = 0; j < 64; j++) acc += xm[j] * w1[j * 64 + t];
    float g = bn2p[t], be = bn2p[64 + t], m = bn2p[128 + t], v = bn2p[192 + t];
    float s = g * rsqrtf(v + EPSBN);
    x2[t] = relu(acc * s + (be - m * s));
    __syncthreads();
    if (t < 9) {
        float a = b2[t];
        for (int j = 0; j < 64; j++) a += x2[j] * w2[j * 9 + t];
        transform[b * 9 + t] = a;
    }
}

// ---------------- K3: pct = inputs @ transform ----------------
__global__ __launch_bounds__(256) void k_pct(const float* __restrict__ inp,
                                             const float* __restrict__ transform,
                                             float* __restrict__ pct) {
    int b = blockIdx.y;
    int n = blockIdx.x * 256 + threadIdx.x;
    __shared__ float T[9];
    if (threadIdx.x < 9) T[threadIdx.x] = transform[b * 9 + threadIdx.x];
    __syncthreads();
    const float* ip = inp + ((size_t)b * 2048 + n) * 3;
    float x0 = ip[0], x1 = ip[1], x2 = ip[2];
    float* op = pct + ((size_t)b * 2049 + n) * 3;
    op[0] = x0 * T[0] + x1 * T[3] + x2 * T[6];
    op[1] = x0 * T[1] + x1 * T[4] + x2 * T[7];
    op[2] = x0 * T[2] + x1 * T[5] + x2 * T[8];
}

// ---------------- K4: MFMA gather -> 96->128 -> 128->256 -> channel max ----------------
__global__ __launch_bounds__(256) void k_feat(const float* __restrict__ pct,
                                              const int* __restrict__ indices,
                                              const u16* __restrict__ w1t, const float* __restrict__ b1,
                                              const float* __restrict__ bn1p,
                                              const u16* __restrict__ w2t, const float* __restrict__ b2,
                                              const float* __restrict__ bn2p,
                                              u32* __restrict__ maxfeats) {
    __shared__ __align__(16) u16 ftA[4096];   // [32 pts][128] bf16, pitch 256B, swizzled (96 used)
    __shared__ __align__(16) u16 h1B[4096];   // [32][128] bf16, pitch 256B, swizzled
    __shared__ float sB1[128], sS1[128], sT1[128];
    __shared__ float sB2[256], sS2[256], sT2[256];

    int b = blockIdx.y, n0p = blockIdx.x * 32, tid = threadIdx.x;
    if (tid < 128) {
        float g = bn1p[tid], be = bn1p[128 + tid], m = bn1p[256 + tid], v = bn1p[384 + tid];
        float s = g * rsqrtf(v + EPSBN);
        sS1[tid] = s; sT1[tid] = be - m * s; sB1[tid] = b1[tid];
    }
    {
        int c = tid;
        float g = bn2p[c], be = bn2p[256 + c], m = bn2p[512 + c], v = bn2p[768 + c];
        float s = g * rsqrtf(v + EPSBN);
        sS2[c] = s; sT2[c] = be - m * s; sB2[c] = b2[c];
    }
    // gather 32 pts x 32 neighbors x 3 -> ftA bf16 swizzled
    {
        const float* pb = pct + (size_t)b * 2049 * 3;
        const int* ib = indices + ((size_t)b * 2048 + n0p) * 32;
        char* fA = (char*)ftA;
#pragma unroll
        for (int r = 0; r < 4; r++) {
            int i = tid + 256 * r;
            int p = i >> 5, k = i & 31;
            int idx = ib[p * 32 + k];
            const float* s = pb + (size_t)idx * 3;
            int sw = (p & 7) << 4;
            int base = p * 256 + 6 * k;
            *(u16*)(fA + ((base) ^ sw)) = f2bf(s[0]);
            *(u16*)(fA + ((base + 2) ^ sw)) = f2bf(s[1]);
            *(u16*)(fA + ((base + 4) ^ sw)) = f2bf(s[2]);
        }
    }
    __syncthreads();

    int lane = tid & 63, wv = tid >> 6;
    int rw = lane & 15, kq = lane >> 4;
    int axor = (rw & 7) << 4;

    // GEMM A: [32][96] x W1T[128][96]
    {
        f32x4 acc[2][2];
#pragma unroll
        for (int m = 0; m < 2; m++)
#pragma unroll
            for (int n = 0; n < 2; n++) acc[m][n] = (f32x4){0.f, 0.f, 0.f, 0.f};
        const char* fA = (const char*)ftA;
        const char* W = (const char*)w1t;
        int nb = wv * 32;
#pragma unroll
        for (int ks = 0; ks < 3; ks++) {
            bf16x8 a0 = *(const bf16x8*)(fA + ((rw * 256 + ks * 64 + kq * 16) ^ axor));
            bf16x8 a1 = *(const bf16x8*)(fA + (((rw + 16) * 256 + ks * 64 + kq * 16) ^ axor));
            bf16x8 b0 = *(const bf16x8*)(W + ((nb + rw) * 192 + ks * 64 + kq * 16));
            bf16x8 b1v = *(const bf16x8*)(W + ((nb + 16 + rw) * 192 + ks * 64 + kq * 16));
            acc[0][0] = MFMA16(a0, b0, acc[0][0]);
            acc[1][0] = MFMA16(a1, b0, acc[1][0]);
            acc[0][1] = MFMA16(a0, b1v, acc[0][1]);
            acc[1][1] = MFMA16(a1, b1v, acc[1][1]);
        }
        char* hB = (char*)h1B;
#pragma unroll
        for (int nt = 0; nt < 2; nt++) {
            int c = nb + nt * 16 + rw;
            float s = sS1[c], t = sT1[c], bi = sB1[c];
#pragma unroll
            for (int m = 0; m < 2; m++)
#pragma unroll
                for (int r = 0; r < 4; r++) {
                    int rr = m * 16 + kq * 4 + r;
                    float h = relu((acc[m][nt][r] + bi) * s + t);
                    *(u16*)(hB + ((rr * 256 + c * 2) ^ ((rr & 7) << 4))) = f2bf(h);
                }
        }
    }
    __syncthreads();
    // GEMM B: [32][128] x W2T[256][128], then channel max
    {
        f32x4 acc[2][4];
#pragma unroll
        for (int m = 0; m < 2; m++)
#pragma unroll
            for (int n = 0; n < 4; n++) acc[m][n] = (f32x4){0.f, 0.f, 0.f, 0.f};
        const char* hB = (const char*)h1B;
        const char* W = (const char*)w2t;
        int nb = wv * 64;
#pragma unroll
        for (int ks = 0; ks < 4; ks++) {
            bf16x8 a0 = *(const bf16x8*)(hB + ((rw * 256 + ks * 64 + kq * 16) ^ axor));
            bf16x8 a1 = *(const bf16x8*)(hB + (((rw + 16) * 256 + ks * 64 + kq * 16) ^ axor));
#pragma unroll
            for (int nt = 0; nt < 4; nt++) {
                bf16x8 bv = *(const bf16x8*)(W + ((nb + nt * 16 + rw) * 256 + ks * 64 + kq * 16));
                acc[0][nt] = MFMA16(a0, bv, acc[0][nt]);
                acc[1][nt] = MFMA16(a1, bv, acc[1][nt]);
            }
        }
#pragma unroll
        for (int nt = 0; nt < 4; nt++) {
            int c = nb + nt * 16 + rw;
            float s = sS2[c], t = sT2[c], bi = sB2[c];
            float vm = 0.f;
#pragma unroll
            for (int m = 0; m < 2; m++)
#pragma unroll
                for (int r = 0; r < 4; r++)
                    vm = fmaxf(vm, relu((acc[m][nt][r] + bi) * s + t));
            vm = fmaxf(vm, __shfl_xor(vm, 16));
            vm = fmaxf(vm, __shfl_xor(vm, 32));
            if (kq == 0) atomicMax(&maxfeats[b * 256 + c], __float_as_uint(vm));
        }
    }
}

// ---------------- K5: single g-row per batch -> pct row 2048 ----------------
__global__ __launch_bounds__(256) void k_gvec(const u32* __restrict__ maxfeats,
                                              const float* __restrict__ bn3p,
                                              const float* __restrict__ dw, const float* __restrict__ db,
                                              float* __restrict__ pct) {
    int b = blockIdx.x, c = threadIdx.x;
    __shared__ float red[3][256];
    float mf = __uint_as_float(maxfeats[b * 256 + c]);
    float g = bn3p[c], be = bn3p[256 + c], m = bn3p[512 + c], v = bn3p[768 + c];
    float s = g * rsqrtf(v + EPSBN);
    float y = mf * s + (be - m * s);
    red[0][c] = y * dw[c * 3 + 0];
    red[1][c] = y * dw[c * 3 + 1];
    red[2][c] = y * dw[c * 3 + 2];
    __syncthreads();
    for (int st = 128; st > 0; st >>= 1) {
        if (c < st) {
            red[0][c] += red[0][c + st];
            red[1][c] += red[1][c + st];
            red[2][c] += red[2][c + st];
        }
        __syncthreads();
    }
    if (c < 3) pct[((size_t)b * 2049 + 2048) * 3 + c] = red[c][0] + db[c];
}

// ---------------- K6: MFMA 3->512->256->128 + row max ----------------
__global__ __launch_bounds__(256) void k_mlp(const float* __restrict__ pct,
                                             const float* __restrict__ w3, const float* __restrict__ b3,
                                             const float* __restrict__ bn4p,
                                             const u16* __restrict__ w4t, const float* __restrict__ b4f,
                                             const float* __restrict__ bn5p,
                                             const u16* __restrict__ w5t, const float* __restrict__ b5f,
                                             const float* __restrict__ bn6p,
                                             u32* __restrict__ netmax) {
    __shared__ __align__(16) u16 hA[16384];  // [32][512] bf16 pitch 1024B swizzled
    __shared__ __align__(16) u16 hB[8192];   // [32][256] bf16 pitch 512B swizzled
    __shared__ float rowsS[128];
    __shared__ float sB4[256], sS5[256], sT5[256];
    __shared__ float sB5[128], sS6[128], sT6[128];

    int b = blockIdx.y, r0 = blockIdx.x * 32, tid = threadIdx.x;
    int nrows = 2049 - r0; if (nrows > 32) nrows = 32;

    {
        int c = tid;
        float g = bn5p[c], be = bn5p[256 + c], m = bn5p[512 + c], v = bn5p[768 + c];
        float s = g * rsqrtf(v + EPSBN);
        sS5[c] = s; sT5[c] = be - m * s; sB4[c] = b4f[c];
    }
    if (tid < 128) {
        int c = tid;
        float g = bn6p[c], be = bn6p[128 + c], m = bn6p[256 + c], v = bn6p[384 + c];
        float s = g * rsqrtf(v + EPSBN);
        sS6[c] = s; sT6[c] = be - m * s; sB5[c] = b5f[c];
    }
    if (tid < 32) {
        float v0 = 0.f, v1 = 0.f, v2 = 0.f;
        if (tid < nrows) {
            const float* s = pct + ((size_t)b * 2049 + r0 + tid) * 3;
            v0 = s[0]; v1 = s[1]; v2 = s[2];
        }
        rowsS[tid * 4] = v0; rowsS[tid * 4 + 1] = v1; rowsS[tid * 4 + 2] = v2;
    }
    __syncthreads();
    // phase 1: 3 -> 512 (VALU), write hA bf16 swizzled
    {
        char* hAc = (char*)hA;
#pragma unroll
        for (int half = 0; half < 2; half++) {
            int c = tid + half * 256;
            float w0 = w3[c], w1f = w3[512 + c], w2f = w3[1024 + c];
            float bi = b3[c];
            float g = bn4p[c], be = bn4p[512 + c], m = bn4p[1024 + c], v = bn4p[1536 + c];
            float s = g * rsqrtf(v + EPSBN), t = be - m * s;
#pragma unroll
            for (int p = 0; p < 32; p++) {
                float z = rowsS[p * 4] * w0 + rowsS[p * 4 + 1] * w1f + rowsS[p * 4 + 2] * w2f + bi;
                float h = relu(z * s + t);
                *(u16*)(hAc + ((p * 1024 + c * 2) ^ ((p & 7) << 4))) = f2bf(h);
            }
        }
    }
    __syncthreads();

    int lane = tid & 63, wv = tid >> 6;
    int rw = lane & 15, kq = lane >> 4;
    int axor = (rw & 7) << 4;

    // phase 2: [32][512] x W4T[256][512] -> hB
    {
        f32x4 acc[2][4];
#pragma unroll
        for (int m = 0; m < 2; m++)
#pragma unroll
            for (int n = 0; n < 4; n++) acc[m][n] = (f32x4){0.f, 0.f, 0.f, 0.f};
        const char* A = (const char*)hA;
        const char* W = (const char*)w4t;
        int nb = wv * 64;
        auto lA = [&](int m, int ks) -> bf16x8 {
            return *(const bf16x8*)(A + (((rw + m) * 1024 + ks * 64 + kq * 16) ^ axor));
        };
        auto lB = [&](int nt, int ks) -> bf16x8 {
            return *(const bf16x8*)(W + ((nb + nt * 16 + rw) * 1024 + ks * 64 + kq * 16));
        };
        bf16x8 a0 = lA(0, 0), a1 = lA(16, 0);
        bf16x8 b0 = lB(0, 0), b1v = lB(1, 0), b2v = lB(2, 0), b3v = lB(3, 0);
#pragma unroll
        for (int ks = 0; ks < 16; ks++) {
            bf16x8 na0, na1, nb0, nb1, nb2, nb3;
            if (ks < 15) {
                na0 = lA(0, ks + 1); na1 = lA(16, ks + 1);
                nb0 = lB(0, ks + 1); nb1 = lB(1, ks + 1); nb2 = lB(2, ks + 1); nb3 = lB(3, ks + 1);
            }
            acc[0][0] = MFMA16(a0, b0, acc[0][0]);  acc[1][0] = MFMA16(a1, b0, acc[1][0]);
            acc[0][1] = MFMA16(a0, b1v, acc[0][1]); acc[1][1] = MFMA16(a1, b1v, acc[1][1]);
            acc[0][2] = MFMA16(a0, b2v, acc[0][2]); acc[1][2] = MFMA16(a1, b2v, acc[1][2]);
            acc[0][3] = MFMA16(a0, b3v, acc[0][3]); acc[1][3] = MFMA16(a1, b3v, acc[1][3]);
            if (ks < 15) { a0 = na0; a1 = na1; b0 = nb0; b1v = nb1; b2v = nb2; b3v = nb3; }
        }
        char* HB = (char*)hB;
#pragma unroll
        for (int nt = 0; nt < 4; nt++) {
            int c = nb + nt * 16 + rw;
            float s = sS5[c], t = sT5[c], bi = sB4[c];
#pragma unroll
            for (int m = 0; m < 2; m++)
#pragma unroll
                for (int r = 0; r < 4; r++) {
                    int rr = m * 16 + kq * 4 + r;
                    float h = relu((acc[m][nt][r] + bi) * s + t);
                    *(u16*)(HB + ((rr * 512 + c * 2) ^ ((rr & 7) << 4))) = f2bf(h);
                }
        }
    }
    __syncthreads();
    // phase 3: [32][256] x W5T[128][256], masked row-max, atomic
    {
        f32x4 acc[2][2];
#pragma unroll
        for (int m = 0; m < 2; m++)
#pragma unroll
            for (int n = 0; n < 2; n++) acc[m][n] = (f32x4){0.f, 0.f, 0.f, 0.f};
        const char* A = (const char*)hB;
        const char* W = (const char*)w5t;
        int nb = wv * 32;
#pragma unroll
        for (int ks = 0; ks < 8; ks++) {
            bf16x8 a0 = *(const bf16x8*)(A + ((rw * 512 + ks * 64 + kq * 16) ^ axor));
            bf16x8 a1 = *(const bf16x8*)(A + (((rw + 16) * 512 + ks * 64 + kq * 16) ^ axor));
            bf16x8 w0 = *(const bf16x8*)(W + ((nb + rw) * 512 + ks * 64 + kq * 16));
            bf16x8 w1v = *(const bf16x8*)(W + ((nb + 16 + rw) * 512 + ks * 64 + kq * 16));
            acc[0][0] = MFMA16(a0, w0, acc[0][0]);
            acc[1][0] = MFMA16(a1, w0, acc[1][0]);
            acc[0][1] = MFMA16(a0, w1v, acc[0][1]);
            acc[1][1] = MFMA16(a1, w1v, acc[1][1]);
        }
#pragma unroll
        for (int nt = 0; nt < 2; nt++) {
            int c = nb + nt * 16 + rw;
            float s = sS6[c], t = sT6[c], bi = sB5[c];
            float vm = 0.f;
#pragma unroll
            for (int m = 0; m < 2; m++)
#pragma unroll
                for (int r = 0; r < 4; r++) {
                    int rr = m * 16 + kq * 4 + r;
                    float h = relu((acc[m][nt][r] + bi) * s + t);
                    if (rr < nrows) vm = fmaxf(vm, h);
                }
            vm = fmaxf(vm, __shfl_xor(vm, 16));
            vm = fmaxf(vm, __shfl_xor(vm, 32));
            if (kq == 0) atomicMax(&netmax[b * 128 + c], __float_as_uint(vm));
        }
    }
}

// ---------------- K7: final bn, dtype-aware store ----------------
__global__ __launch_bounds__(256) void k_out(const u32* __restrict__ netmax,
                                             const float* __restrict__ bng,
                                             const u32* __restrict__ flag,
                                             void* __restrict__ out) {
    int i = blockIdx.x * 256 + threadIdx.x;  // 4096
    int c = i & 127;
    float v = __uint_as_float(netmax[i]);
    float g = bng[c], be = bng[128 + c], m = bng[256 + c], va = bng[384 + c];
    float s = g * rsqrtf(va + EPSBN);
    float val = v * s + (be - m * s);
    if (flag[0]) ((u16*)out)[i] = f2bf(val);
    else ((float*)out)[i] = val;
}

extern "C" void kernel_launch(void* const* d_in, const int* in_sizes, int n_in,
                              void* d_out, int out_size, void* d_ws, size_t ws_size,
                              hipStream_t stream) {
    float* ws = (float*)d_ws;
    u32* flag = (u32*)ws;

    static const int order[28] = {0,2,3,4,5,6,7,8,9,10,11,12,13,14,15,16,17,18,19,20,21,22,23,24,25,26,27,28};
    static const int nels[28] = {196608,192,64,256,4096,64,256,576,9,12288,128,512,32768,256,1024,1024,768,3,1536,512,2048,131072,256,1024,32768,128,512,512};
    static const int offs[28] = {A_INPUTS,A_TC1W,A_TC1B,A_TBN1,A_TD1W,A_TD1B,A_TBN2,A_TD2W,A_TD2B,A_C1W,A_C1B,A_BN1,A_C2W,A_C2B,A_BN2,A_BN3,A_D1W,A_D1B,A_C3W,A_C3B,A_BN4,A_BLK1W,A_BLK1B,A_BLK1BN,A_BLK2W,A_BLK2B,A_BLK2BN,A_BNGF};
    ConvArgs ca;
    for (int i = 0; i < 28; i++) { ca.src[i] = d_in[order[i]]; ca.n[i] = nels[i]; ca.off[i] = offs[i]; }

    const int* indices = (const int*)d_in[1];

    k_convert<<<dim3(32, 28), 256, 0, stream>>>(ca, (const u16*)d_in[4], ws, flag);

    // bf16 transposed weights (single launch, 816 blocks)
    PrepArgs pa;
    pa.src[0] = ws + A_C1W;   pa.dst[0] = (u16*)(ws + T_C1WT); pa.K[0] = 96;  pa.logN[0] = 7; pa.base[0] = 0;
    pa.src[1] = ws + A_C2W;   pa.dst[1] = (u16*)(ws + T_C2WT); pa.K[1] = 128; pa.logN[1] = 8; pa.base[1] = 48;
    pa.src[2] = ws + A_BLK1W; pa.dst[2] = (u16*)(ws + T_W4T);  pa.K[2] = 512; pa.logN[2] = 8; pa.base[2] = 176;
    pa.src[3] = ws + A_BLK2W; pa.dst[3] = (u16*)(ws + T_W5T);  pa.K[3] = 256; pa.logN[3] = 7; pa.base[3] = 688;
    k_prepw_all<<<816, 256, 0, stream>>>(pa);

    // zero maxfeats + netmax + xmax (contiguous [S_MAXF, S_XMAX+2048))
    hipMemsetAsync(ws + S_MAXF, 0, (size_t)14336 * 4, stream);

    k_tnet1<<<dim3(4, 32), 256, 0, stream>>>(ws + A_INPUTS, ws + A_TC1W, ws + A_TC1B, ws + A_TBN1,
                                             (u32*)(ws + S_XMAX));
    k_tnet2<<<32, 64, 0, stream>>>((const float*)(ws + S_XMAX), ws + A_TD1W, ws + A_TD1B, ws + A_TBN2,
                                   ws + A_TD2W, ws + A_TD2B, ws + S_TRF);
    k_pct<<<dim3(8, 32), 256, 0, stream>>>(ws + A_INPUTS, ws + S_TRF, ws + S_PCT);
    k_feat<<<dim3(64, 32), 256, 0, stream>>>(ws + S_PCT, indices,
                                             (const u16*)(ws + T_C1WT), ws + A_C1B, ws + A_BN1,
                                             (const u16*)(ws + T_C2WT), ws + A_C2B, ws + A_BN2,
                                             (u32*)(ws + S_MAXF));
    k_gvec<<<32, 256, 0, stream>>>((u32*)(ws + S_MAXF), ws + A_BN3, ws + A_D1W, ws + A_D1B, ws + S_PCT);
    k_mlp<<<dim3(65, 32), 256, 0, stream>>>(ws + S_PCT,
                                            ws + A_C3W, ws + A_C3B, ws + A_BN4,
                                            (const u16*)(ws + T_W4T), ws + A_BLK1B, ws + A_BLK1BN,
                                            (const u16*)(ws + T_W5T), ws + A_BLK2B, ws + A_BLK2BN,
                                            (u32*)(ws + S_NETMAX));
    k_out<<<16, 256, 0, stream>>>((u32*)(ws + S_NETMAX), ws + A_BNGF, flag, d_out);
}

// Round 5
// 223.767 us; speedup vs baseline: 3.4837x; 1.2118x over previous
//
#include <hip/hip_runtime.h>

typedef unsigned short u16;
typedef unsigned int u32;
typedef __attribute__((ext_vector_type(8))) short bf16x8;
typedef __attribute__((ext_vector_type(4))) float f32x4;

#define EPSBN 0.001f
#define MFMA16(a, b, c) __builtin_amdgcn_mfma_f32_16x16x32_bf16(a, b, c, 0, 0, 0)

__device__ __forceinline__ float bf2f(u16 u) {
    return __uint_as_float(((u32)u) << 16);
}
__device__ __forceinline__ u16 f2bf(float f) {
    u32 u = __float_as_uint(f);
    u32 r = u + 0x7FFFu + ((u >> 16) & 1u);
    return (u16)(r >> 16);
}
__device__ __forceinline__ float relu(float x) { return x > 0.f ? x : 0.f; }

// ---------------- ws layout (float offsets) ----------------
#define A_INPUTS 64       // 196608
#define A_TC1W  196672
#define A_TC1B  196864
#define A_TBN1  196928
#define A_TD1W  197184
#define A_TD1B  201280
#define A_TBN2  201344
#define A_TD2W  201600
#define A_TD2B  202176
#define A_C1W   202240    // 12288 (conv1_w 96x128)
#define A_C1B   214528
#define A_BN1   214656
#define A_C2W   215168    // 32768 (conv2_w 128x256)
#define A_C2B   247936
#define A_BN2   248192
#define A_BN3   249216
#define A_D1W   250240
#define A_D1B   251008
#define A_C3W   251072    // 1536 (conv3_w 3x512)
#define A_C3B   252608
#define A_BN4   253120
#define A_BLK1W 255168    // 131072 (blk1_w 512x256)
#define A_BLK1B 386240
#define A_BLK1BN 386496
#define A_BLK2W 387520    // 32768 (blk2_w 256x128)
#define A_BLK2B 420288
#define A_BLK2BN 420416
#define A_BNGF  420928
#define S_TRF   423488
#define S_PCT   423808    // 196704 (32*2049*3 f32)
// zeroed region: [S_MAXF, S_XMAX+2048) = 14336 floats
#define S_MAXF  620544    // 8192 u32
#define S_NETMAX 628736   // 4096 u32
#define S_XMAX  632832    // 2048 u32
// bf16 transposed+scaled weight arenas (u16 stored in float space)
#define T_C1WT  634880    // 128x96  u16 = 6144 floats
#define T_C2WT  641024    // 256x128 u16 = 16384 floats
#define T_W4T   657408    // 256x512 u16 = 65536 floats
#define T_W5T   722944    // 128x256 u16 = 16384 floats
// folded small params (f32)
#define P_W3S   739328    // 1536 (w3 * s4, [3][512])
#define P_B3S   740864    // 512  (b3*s4 + t4)
#define P_BP1   741376    // 128  (b1*s1 + t1)
#define P_BP2   741504    // 256  (b2*s2 + t2)
#define P_BP4   741760    // 256  (b4*s5 + t5)
#define P_BP5   742016    // 128  (b5*s6 + t6)
// end 742144 floats = 2.97 MB

struct ConvArgs {
    const void* src[28];
    int n[28];
    int off[28];
};

struct PrepArgs {
    const float* src[4];
    const float* bn[4];   // bn params [4][N] for output-channel scale
    u16* dst[4];
    int K[4];
    int logN[4];
    int base[4];
};

// ---------------- convert all float tensors to f32 arena (+inline dtype detect) ----------------
__global__ __launch_bounds__(256) void k_convert(ConvArgs a, const u16* __restrict__ tbn1,
                                                 float* __restrict__ ws, u32* __restrict__ flag) {
    int ok = 1;
    for (int i = 0; i < 16; i += 2) {
        u16 v = tbn1[i];
        if (v < 0x3E00u || v > 0x4080u) ok = 0;
    }
    if (blockIdx.x == 0 && blockIdx.y == 0 && threadIdx.x == 0) flag[0] = ok ? 1u : 0u;

    int t = blockIdx.y;
    int n = a.n[t];
    int cpb = (n + 31) >> 5;
    int s = blockIdx.x * cpb;
    int e = s + cpb; if (e > n) e = n;
    float* dst = ws + a.off[t];
    if (ok) {
        const u16* src = (const u16*)a.src[t];
        for (int i = s + (int)threadIdx.x; i < e; i += 256) dst[i] = bf2f(src[i]);
    } else {
        const float* src = (const float*)a.src[t];
        for (int i = s + (int)threadIdx.x; i < e; i += 256) dst[i] = src[i];
    }
}

// ---------------- prep: bf16 transposed + bn-scaled weights  dst[c*K+k] = src[k*N+c]*s[c] ----------------
__global__ __launch_bounds__(256) void k_prepw_all(PrepArgs pa) {
    int blk = blockIdx.x;
    int t = (blk < 48) ? 0 : (blk < 176) ? 1 : (blk < 688) ? 2 : 3;
    int i = (blk - pa.base[t]) * 256 + (int)threadIdx.x;
    int N = 1 << pa.logN[t];
    int k = i >> pa.logN[t], c = i & (N - 1);
    const float* bn = pa.bn[t];
    float s = bn[c] * rsqrtf(bn[3 * N + c] + EPSBN);
    pa.dst[t][c * pa.K[t] + k] = f2bf(pa.src[t][i] * s);
}

// ---------------- prep: folded small params (1 block) ----------------
__global__ __launch_bounds__(256) void k_prepsmall(float* __restrict__ ws) {
    int tid = threadIdx.x;
    // w3s/b3s (bn4, N=512)
    for (int c = tid; c < 512; c += 256) {
        const float* bn = ws + A_BN4;
        float s = bn[c] * rsqrtf(bn[1536 + c] + EPSBN);
        float t = bn[512 + c] - bn[1024 + c] * s;
        ws[P_W3S + c]        = ws[A_C3W + c] * s;
        ws[P_W3S + 512 + c]  = ws[A_C3W + 512 + c] * s;
        ws[P_W3S + 1024 + c] = ws[A_C3W + 1024 + c] * s;
        ws[P_B3S + c] = ws[A_C3B + c] * s + t;
    }
    // bp2 (bn2 N=256), bp4 (blk1_bn N=256)
    {
        int c = tid;
        const float* bn2 = ws + A_BN2;
        float s2 = bn2[c] * rsqrtf(bn2[768 + c] + EPSBN);
        ws[P_BP2 + c] = ws[A_C2B + c] * s2 + (bn2[256 + c] - bn2[512 + c] * s2);
        const float* bn5 = ws + A_BLK1BN;
        float s5 = bn5[c] * rsqrtf(bn5[768 + c] + EPSBN);
        ws[P_BP4 + c] = ws[A_BLK1B + c] * s5 + (bn5[256 + c] - bn5[512 + c] * s5);
    }
    // bp1 (bn1 N=128), bp5 (blk2_bn N=128)
    if (tid < 128) {
        int c = tid;
        const float* bn1 = ws + A_BN1;
        float s1 = bn1[c] * rsqrtf(bn1[384 + c] + EPSBN);
        ws[P_BP1 + c] = ws[A_C1B + c] * s1 + (bn1[128 + c] - bn1[256 + c] * s1);
        const float* bn6 = ws + A_BLK2BN;
        float s6 = bn6[c] * rsqrtf(bn6[384 + c] + EPSBN);
        ws[P_BP5 + c] = ws[A_BLK2B + c] * s6 + (bn6[128 + c] - bn6[256 + c] * s6);
    }
}

// ---------------- K1: t-net stage 1 ----------------
__global__ __launch_bounds__(256) void k_tnet1(const float* __restrict__ inp,
                                               const float* __restrict__ w,
                                               const float* __restrict__ bias,
                                               const float* __restrict__ bn,
                                               u32* __restrict__ xmax) {
    __shared__ float pts[1536];
    __shared__ float wred[4][64];
    int b = blockIdx.y, slice = blockIdx.x, tid = threadIdx.x;
    const float* ip = inp + ((size_t)b * 2048 + slice * 512) * 3;
#pragma unroll
    for (int i = 0; i < 6; i++) pts[tid + i * 256] = ip[tid + i * 256];

    int c = tid & 63, np = tid >> 6;
    float w0 = w[c], w1 = w[64 + c], w2 = w[128 + c], bi = bias[c];
    float g = bn[c], be = bn[64 + c], m = bn[128 + c], v = bn[192 + c];
    float s = g * rsqrtf(v + EPSBN), t = be - m * s;
    __syncthreads();

    float vmax = 0.f;
    int pbase = np * 128;
#pragma unroll 4
    for (int p = 0; p < 128; p++) {
        float x0 = pts[(pbase + p) * 3], x1 = pts[(pbase + p) * 3 + 1], x2 = pts[(pbase + p) * 3 + 2];
        float z = x0 * w0 + x1 * w1 + x2 * w2 + bi;
        vmax = fmaxf(vmax, z * s + t);
    }
    wred[np][c] = vmax;
    __syncthreads();
    if (tid < 64) {
        float mm = fmaxf(fmaxf(wred[0][tid], wred[1][tid]), fmaxf(wred[2][tid], wred[3][tid]));
        atomicMax(&xmax[b * 64 + tid], __float_as_uint(relu(mm)));
    }
}

// ---------------- K2: t-net stage 2 ----------------
__global__ __launch_bounds__(64) void k_tnet2(const float* __restrict__ xmax,
                                              const float* __restrict__ w1, const float* __restrict__ b1,
                                              const float* __restrict__ bn2p,
                                              const float* __restrict__ w2, const float* __restrict__ b2,
                                              float* __restrict__ transform) {
    int b = blockIdx.x, t = threadIdx.x;
    __shared__ float x2[64];
    const float* xm = xmax + b * 64;
    float acc = b1[t];
    for (int j = 0; j < 64; j++) acc += xm[j] * w1[j * 64 + t];
    float g = bn2p[t], be = bn2p[64 + t], m = bn2p[128 + t], v = bn2p[192 + t];
    float s = g * rsqrtf(v + EPSBN);
    x2[t] = relu(acc * s + (be - m * s));
    __syncthreads();
    if (t < 9) {
        float a = b2[t];
        for (int j = 0; j < 64; j++) a += x2[j] * w2[j * 9 + t];
        transform[b * 9 + t] = a;
    }
}

// ---------------- K3: pct = inputs @ transform ----------------
__global__ __launch_bounds__(256) void k_pct(const float* __restrict__ inp,
                                             const float* __restrict__ transform,
                                             float* __restrict__ pct) {
    int b = blockIdx.y;
    int n = blockIdx.x * 256 + threadIdx.x;
    __shared__ float T[9];
    if (threadIdx.x < 9) T[threadIdx.x] = transform[b * 9 + threadIdx.x];
    __syncthreads();
    const float* ip = inp + ((size_t)b * 2048 + n) * 3;
    float x0 = ip[0], x1 = ip[1], x2 = ip[2];
    float* op = pct + ((size_t)b * 2049 + n) * 3;
    op[0] = x0 * T[0] + x1 * T[3] + x2 * T[6];
    op[1] = x0 * T[1] + x1 * T[4] + x2 * T[7];
    op[2] = x0 * T[2] + x1 * T[5] + x2 * T[8];
}

// ---------------- K4: MFMA M=64: gather -> 96->128 -> 128->256 -> channel max ----------------
__global__ __launch_bounds__(256, 3) void k_feat(const float* __restrict__ pct,
                                                 const int* __restrict__ indices,
                                                 const u16* __restrict__ w1t, const float* __restrict__ bp1,
                                                 const u16* __restrict__ w2t, const float* __restrict__ bp2,
                                                 u32* __restrict__ maxfeats) {
    __shared__ __align__(16) u16 ftA[8192];   // [64 pts][128] pitch 256B, swizzled (96 used)
    __shared__ __align__(16) u16 h1B[8192];   // [64][128] pitch 256B, swizzled
    __shared__ float sp1[128], sp2[256];

    int b = blockIdx.y, n0p = blockIdx.x * 64, tid = threadIdx.x;
    sp2[tid] = bp2[tid];
    if (tid < 128) sp1[tid] = bp1[tid];
    // gather 64 pts x 32 neighbors x 3 -> ftA bf16 swizzled
    {
        const float* pb = pct + (size_t)b * 2049 * 3;
        const int* ib = indices + ((size_t)b * 2048 + n0p) * 32;
        char* fA = (char*)ftA;
#pragma unroll
        for (int r = 0; r < 8; r++) {
            int i = tid + 256 * r;
            int p = i >> 5, k = i & 31;
            int idx = ib[p * 32 + k];
            const float* s = pb + (size_t)idx * 3;
            int sw = (p & 7) << 4;
            int base = p * 256 + 6 * k;
            *(u16*)(fA + ((base) ^ sw))     = f2bf(s[0]);
            *(u16*)(fA + ((base + 2) ^ sw)) = f2bf(s[1]);
            *(u16*)(fA + ((base + 4) ^ sw)) = f2bf(s[2]);
        }
    }
    __syncthreads();

    int lane = tid & 63, wv = tid >> 6;
    int rw = lane & 15, kq = lane >> 4;
    int axor = (rw & 7) << 4;

    // GEMM A: [64][96] x W1T[128][96]  (4 waves split N=128 -> 32 each)
    {
        f32x4 acc[4][2];
#pragma unroll
        for (int m = 0; m < 4; m++)
#pragma unroll
            for (int n = 0; n < 2; n++) acc[m][n] = (f32x4){0.f, 0.f, 0.f, 0.f};
        const char* A = (const char*)ftA;
        const char* W = (const char*)w1t;
        int nb = wv * 32;
#pragma unroll
        for (int ks = 0; ks < 3; ks++) {
            int kb = ks * 64 + kq * 16;
            bf16x8 b0 = *(const bf16x8*)(W + (nb + rw) * 192 + kb);
            bf16x8 b1 = *(const bf16x8*)(W + (nb + 16 + rw) * 192 + kb);
            bf16x8 a0 = *(const bf16x8*)(A + (((rw) * 256 + kb) ^ axor));
            bf16x8 a1 = *(const bf16x8*)(A + (((rw + 16) * 256 + kb) ^ axor));
            bf16x8 a2 = *(const bf16x8*)(A + (((rw + 32) * 256 + kb) ^ axor));
            bf16x8 a3 = *(const bf16x8*)(A + (((rw + 48) * 256 + kb) ^ axor));
            acc[0][0] = MFMA16(a0, b0, acc[0][0]); acc[0][1] = MFMA16(a0, b1, acc[0][1]);
            acc[1][0] = MFMA16(a1, b0, acc[1][0]); acc[1][1] = MFMA16(a1, b1, acc[1][1]);
            acc[2][0] = MFMA16(a2, b0, acc[2][0]); acc[2][1] = MFMA16(a2, b1, acc[2][1]);
            acc[3][0] = MFMA16(a3, b0, acc[3][0]); acc[3][1] = MFMA16(a3, b1, acc[3][1]);
        }
        char* hB = (char*)h1B;
#pragma unroll
        for (int nt = 0; nt < 2; nt++) {
            int c = nb + nt * 16 + rw;
            float bb = sp1[c];
#pragma unroll
            for (int m = 0; m < 4; m++)
#pragma unroll
                for (int r = 0; r < 4; r++) {
                    int rr = m * 16 + kq * 4 + r;
                    float h = relu(acc[m][nt][r] + bb);
                    *(u16*)(hB + ((rr * 256 + c * 2) ^ ((rr & 7) << 4))) = f2bf(h);
                }
        }
    }
    __syncthreads();
    // GEMM B: [64][128] x W2T[256][128], then channel max
    {
        f32x4 acc[4][4];
#pragma unroll
        for (int m = 0; m < 4; m++)
#pragma unroll
            for (int n = 0; n < 4; n++) acc[m][n] = (f32x4){0.f, 0.f, 0.f, 0.f};
        const char* A = (const char*)h1B;
        const char* W = (const char*)w2t;
        int nb = wv * 64;
#pragma unroll
        for (int ks = 0; ks < 4; ks++) {
            int kb = ks * 64 + kq * 16;
            bf16x8 a0 = *(const bf16x8*)(A + (((rw) * 256 + kb) ^ axor));
            bf16x8 a1 = *(const bf16x8*)(A + (((rw + 16) * 256 + kb) ^ axor));
            bf16x8 a2 = *(const bf16x8*)(A + (((rw + 32) * 256 + kb) ^ axor));
            bf16x8 a3 = *(const bf16x8*)(A + (((rw + 48) * 256 + kb) ^ axor));
#pragma unroll
            for (int nt = 0; nt < 4; nt++) {
                bf16x8 bv = *(const bf16x8*)(W + (nb + nt * 16 + rw) * 256 + kb);
                acc[0][nt] = MFMA16(a0, bv, acc[0][nt]);
                acc[1][nt] = MFMA16(a1, bv, acc[1][nt]);
                acc[2][nt] = MFMA16(a2, bv, acc[2][nt]);
                acc[3][nt] = MFMA16(a3, bv, acc[3][nt]);
            }
        }
#pragma unroll
        for (int nt = 0; nt < 4; nt++) {
            int c = nb + nt * 16 + rw;
            float bb = sp2[c];
            float vm = 0.f;
#pragma unroll
            for (int m = 0; m < 4; m++)
#pragma unroll
                for (int r = 0; r < 4; r++)
                    vm = fmaxf(vm, relu(acc[m][nt][r] + bb));
            vm = fmaxf(vm, __shfl_xor(vm, 16));
            vm = fmaxf(vm, __shfl_xor(vm, 32));
            if (kq == 0) atomicMax(&maxfeats[b * 256 + c], __float_as_uint(vm));
        }
    }
}

// ---------------- K5: single g-row per batch -> pct row 2048 ----------------
__global__ __launch_bounds__(256) void k_gvec(const u32* __restrict__ maxfeats,
                                              const float* __restrict__ bn3p,
                                              const float* __restrict__ dw, const float* __restrict__ db,
                                              float* __restrict__ pct) {
    int b = blockIdx.x, c = threadIdx.x;
    __shared__ float red[3][256];
    float mf = __uint_as_float(maxfeats[b * 256 + c]);
    float g = bn3p[c], be = bn3p[256 + c], m = bn3p[512 + c], v = bn3p[768 + c];
    float s = g * rsqrtf(v + EPSBN);
    float y = mf * s + (be - m * s);
    red[0][c] = y * dw[c * 3 + 0];
    red[1][c] = y * dw[c * 3 + 1];
    red[2][c] = y * dw[c * 3 + 2];
    __syncthreads();
    for (int st = 128; st > 0; st >>= 1) {
        if (c < st) {
            red[0][c] += red[0][c + st];
            red[1][c] += red[1][c + st];
            red[2][c] += red[2][c + st];
        }
        __syncthreads();
    }
    if (c < 3) pct[((size_t)b * 2049 + 2048) * 3 + c] = red[c][0] + db[c];
}

// ---------------- K6: MFMA M=64, chunked 3->512 || 512->256, then 256->128 + row max ----------------
__global__ __launch_bounds__(256, 3) void k_mlp(const float* __restrict__ pct,
                                                const float* __restrict__ w3s, const float* __restrict__ b3s,
                                                const u16* __restrict__ w4t, const float* __restrict__ bp4,
                                                const u16* __restrict__ w5t, const float* __restrict__ bp5,
                                                u32* __restrict__ netmax) {
    __shared__ __align__(16) u16 hA[2][4096];  // ping-pong [64 rows][64 k] pitch 128B swizzled
    __shared__ __align__(16) u16 hB[16384];    // [64][256] pitch 512B swizzled
    __shared__ float rows4[256];               // [64][4]
    __shared__ float sb4[256], sb5[128];

    int b = blockIdx.y, r0 = blockIdx.x * 64, tid = threadIdx.x;
    int nrows = 2049 - r0; if (nrows > 64) nrows = 64;

    sb4[tid] = bp4[tid];
    if (tid < 128) sb5[tid] = bp5[tid];
    if (tid < 64) {
        float v0 = 0.f, v1 = 0.f, v2 = 0.f;
        if (tid < nrows) {
            const float* s = pct + ((size_t)b * 2049 + r0 + tid) * 3;
            v0 = s[0]; v1 = s[1]; v2 = s[2];
        }
        rows4[tid * 4] = v0; rows4[tid * 4 + 1] = v1; rows4[tid * 4 + 2] = v2;
    }
    __syncthreads();

    int lane = tid & 63, wv = tid >> 6;
    int rw = lane & 15, kq = lane >> 4;
    int axor = (rw & 7) << 4;
    int chv = tid & 63;      // channel within 64-wide chunk
    int rquart = tid >> 6;   // row quarter

    // phase1: compute h512 chunk c (64 channels) into buffer bufi
    auto phase1 = [&](int c, int bufi) {
        int ch = c * 64 + chv;
        float w0 = w3s[ch], w1 = w3s[512 + ch], w2 = w3s[1024 + ch], bb = b3s[ch];
        char* dst = (char*)hA[bufi];
#pragma unroll
        for (int r = 0; r < 16; r++) {
            int row = rquart * 16 + r;
            float x0 = rows4[row * 4], x1 = rows4[row * 4 + 1], x2 = rows4[row * 4 + 2];
            float h = relu(x0 * w0 + x1 * w1 + x2 * w2 + bb);
            *(u16*)(dst + ((row * 128 + chv * 2) ^ ((row & 7) << 4))) = f2bf(h);
        }
    };

    phase1(0, 0);
    __syncthreads();

    // phase 2: [64][512] x W4T[256][512] -> hB, K in 8 chunks of 64
    {
        f32x4 acc[4][4];
#pragma unroll
        for (int m = 0; m < 4; m++)
#pragma unroll
            for (int n = 0; n < 4; n++) acc[m][n] = (f32x4){0.f, 0.f, 0.f, 0.f};
        const char* W = (const char*)w4t;
        int nb = wv * 64;
        for (int c = 0; c < 8; c++) {
            // issue B loads for this chunk first (hide under phase1 VALU)
            bf16x8 bfr[2][4];
#pragma unroll
            for (int ksl = 0; ksl < 2; ksl++)
#pragma unroll
                for (int nt = 0; nt < 4; nt++)
                    bfr[ksl][nt] = *(const bf16x8*)(W + (nb + nt * 16 + rw) * 1024 + c * 128 + ksl * 64 + kq * 16);
            if (c < 7) phase1(c + 1, (c + 1) & 1);
            const char* A = (const char*)hA[c & 1];
#pragma unroll
            for (int ksl = 0; ksl < 2; ksl++) {
                int kb = ksl * 64 + kq * 16;
                bf16x8 a0 = *(const bf16x8*)(A + (((rw) * 128 + kb) ^ axor));
                bf16x8 a1 = *(const bf16x8*)(A + (((rw + 16) * 128 + kb) ^ axor));
                bf16x8 a2 = *(const bf16x8*)(A + (((rw + 32) * 128 + kb) ^ axor));
                bf16x8 a3 = *(const bf16x8*)(A + (((rw + 48) * 128 + kb) ^ axor));
#pragma unroll
                for (int nt = 0; nt < 4; nt++) {
                    acc[0][nt] = MFMA16(a0, bfr[ksl][nt], acc[0][nt]);
                    acc[1][nt] = MFMA16(a1, bfr[ksl][nt], acc[1][nt]);
                    acc[2][nt] = MFMA16(a2, bfr[ksl][nt], acc[2][nt]);
                    acc[3][nt] = MFMA16(a3, bfr[ksl][nt], acc[3][nt]);
                }
            }
            __syncthreads();
        }
        char* HB = (char*)hB;
#pragma unroll
        for (int nt = 0; nt < 4; nt++) {
            int c = nb + nt * 16 + rw;
            float bb = sb4[c];
#pragma unroll
            for (int m = 0; m < 4; m++)
#pragma unroll
                for (int r = 0; r < 4; r++) {
                    int rr = m * 16 + kq * 4 + r;
                    float h = relu(acc[m][nt][r] + bb);
                    *(u16*)(HB + ((rr * 512 + c * 2) ^ ((rr & 7) << 4))) = f2bf(h);
                }
        }
    }
    __syncthreads();
    // phase 3: [64][256] x W5T[128][256], masked row-max, atomic
    {
        f32x4 acc[4][2];
#pragma unroll
        for (int m = 0; m < 4; m++)
#pragma unroll
            for (int n = 0; n < 2; n++) acc[m][n] = (f32x4){0.f, 0.f, 0.f, 0.f};
        const char* A = (const char*)hB;
        const char* W = (const char*)w5t;
        int nb = wv * 32;
#pragma unroll
        for (int ks = 0; ks < 8; ks++) {
            int kb = ks * 64 + kq * 16;
            bf16x8 b0 = *(const bf16x8*)(W + (nb + rw) * 512 + kb);
            bf16x8 b1 = *(const bf16x8*)(W + (nb + 16 + rw) * 512 + kb);
            bf16x8 a0 = *(const bf16x8*)(A + (((rw) * 512 + kb) ^ axor));
            bf16x8 a1 = *(const bf16x8*)(A + (((rw + 16) * 512 + kb) ^ axor));
            bf16x8 a2 = *(const bf16x8*)(A + (((rw + 32) * 512 + kb) ^ axor));
            bf16x8 a3 = *(const bf16x8*)(A + (((rw + 48) * 512 + kb) ^ axor));
            acc[0][0] = MFMA16(a0, b0, acc[0][0]); acc[0][1] = MFMA16(a0, b1, acc[0][1]);
            acc[1][0] = MFMA16(a1, b0, acc[1][0]); acc[1][1] = MFMA16(a1, b1, acc[1][1]);
            acc[2][0] = MFMA16(a2, b0, acc[2][0]); acc[2][1] = MFMA16(a2, b1, acc[2][1]);
            acc[3][0] = MFMA16(a3, b0, acc[3][0]); acc[3][1] = MFMA16(a3, b1, acc[3][1]);
        }
#pragma unroll
        for (int nt = 0; nt < 2; nt++) {
            int c = nb + nt * 16 + rw;
            float bb = sb5[c];
            float vm = 0.f;
#pragma unroll
            for (int m = 0; m < 4; m++)
#pragma unroll
                for (int r = 0; r < 4; r++) {
                    int rr = m * 16 + kq * 4 + r;
                    float h = relu(acc[m][nt][r] + bb);
                    if (rr < nrows) vm = fmaxf(vm, h);
                }
            vm = fmaxf(vm, __shfl_xor(vm, 16));
            vm = fmaxf(vm, __shfl_xor(vm, 32));
            if (kq == 0) atomicMax(&netmax[b * 128 + c], __float_as_uint(vm));
        }
    }
}

// ---------------- K7: final bn, dtype-aware store ----------------
__global__ __launch_bounds__(256) void k_out(const u32* __restrict__ netmax,
                                             const float* __restrict__ bng,
                                             const u32* __restrict__ flag,
                                             void* __restrict__ out) {
    int i = blockIdx.x * 256 + threadIdx.x;  // 4096
    int c = i & 127;
    float v = __uint_as_float(netmax[i]);
    float g = bng[c], be = bng[128 + c], m = bng[256 + c], va = bng[384 + c];
    float s = g * rsqrtf(va + EPSBN);
    float val = v * s + (be - m * s);
    if (flag[0]) ((u16*)out)[i] = f2bf(val);
    else ((float*)out)[i] = val;
}

extern "C" void kernel_launch(void* const* d_in, const int* in_sizes, int n_in,
                              void* d_out, int out_size, void* d_ws, size_t ws_size,
                              hipStream_t stream) {
    float* ws = (float*)d_ws;
    u32* flag = (u32*)ws;

    static const int order[28] = {0,2,3,4,5,6,7,8,9,10,11,12,13,14,15,16,17,18,19,20,21,22,23,24,25,26,27,28};
    static const int nels[28] = {196608,192,64,256,4096,64,256,576,9,12288,128,512,32768,256,1024,1024,768,3,1536,512,2048,131072,256,1024,32768,128,512,512};
    static const int offs[28] = {A_INPUTS,A_TC1W,A_TC1B,A_TBN1,A_TD1W,A_TD1B,A_TBN2,A_TD2W,A_TD2B,A_C1W,A_C1B,A_BN1,A_C2W,A_C2B,A_BN2,A_BN3,A_D1W,A_D1B,A_C3W,A_C3B,A_BN4,A_BLK1W,A_BLK1B,A_BLK1BN,A_BLK2W,A_BLK2B,A_BLK2BN,A_BNGF};
    ConvArgs ca;
    for (int i = 0; i < 28; i++) { ca.src[i] = d_in[order[i]]; ca.n[i] = nels[i]; ca.off[i] = offs[i]; }

    const int* indices = (const int*)d_in[1];

    k_convert<<<dim3(32, 28), 256, 0, stream>>>(ca, (const u16*)d_in[4], ws, flag);

    // bf16 transposed + bn-scaled weights (single launch, 816 blocks)
    PrepArgs pa;
    pa.src[0] = ws + A_C1W;   pa.bn[0] = ws + A_BN1;    pa.dst[0] = (u16*)(ws + T_C1WT); pa.K[0] = 96;  pa.logN[0] = 7; pa.base[0] = 0;
    pa.src[1] = ws + A_C2W;   pa.bn[1] = ws + A_BN2;    pa.dst[1] = (u16*)(ws + T_C2WT); pa.K[1] = 128; pa.logN[1] = 8; pa.base[1] = 48;
    pa.src[2] = ws + A_BLK1W; pa.bn[2] = ws + A_BLK1BN; pa.dst[2] = (u16*)(ws + T_W4T);  pa.K[2] = 512; pa.logN[2] = 8; pa.base[2] = 176;
    pa.src[3] = ws + A_BLK2W; pa.bn[3] = ws + A_BLK2BN; pa.dst[3] = (u16*)(ws + T_W5T);  pa.K[3] = 256; pa.logN[3] = 7; pa.base[3] = 688;
    k_prepw_all<<<816, 256, 0, stream>>>(pa);
    k_prepsmall<<<1, 256, 0, stream>>>(ws);

    // zero maxfeats + netmax + xmax (contiguous [S_MAXF, S_XMAX+2048))
    hipMemsetAsync(ws + S_MAXF, 0, (size_t)14336 * 4, stream);

    k_tnet1<<<dim3(4, 32), 256, 0, stream>>>(ws + A_INPUTS, ws + A_TC1W, ws + A_TC1B, ws + A_TBN1,
                                             (u32*)(ws + S_XMAX));
    k_tnet2<<<32, 64, 0, stream>>>((const float*)(ws + S_XMAX), ws + A_TD1W, ws + A_TD1B, ws + A_TBN2,
                                   ws + A_TD2W, ws + A_TD2B, ws + S_TRF);
    k_pct<<<dim3(8, 32), 256, 0, stream>>>(ws + A_INPUTS, ws + S_TRF, ws + S_PCT);
    k_feat<<<dim3(32, 32), 256, 0, stream>>>(ws + S_PCT, indices,
                                             (const u16*)(ws + T_C1WT), ws + P_BP1,
                                             (const u16*)(ws + T_C2WT), ws + P_BP2,
                                             (u32*)(ws + S_MAXF));
    k_gvec<<<32, 256, 0, stream>>>((u32*)(ws + S_MAXF), ws + A_BN3, ws + A_D1W, ws + A_D1B, ws + S_PCT);
    k_mlp<<<dim3(33, 32), 256, 0, stream>>>(ws + S_PCT,
                                            ws + P_W3S, ws + P_B3S,
                                            (const u16*)(ws + T_W4T), ws + P_BP4,
                                            (const u16*)(ws + T_W5T), ws + P_BP5,
                                            (u32*)(ws + S_NETMAX));
    k_out<<<16, 256, 0, stream>>>((u32*)(ws + S_NETMAX), ws + A_BNGF, flag, d_out);
}